// Round 10
// baseline (412.654 us; speedup 1.0000x reference)
//
#include <hip/hip_runtime.h>
#include <hip/hip_bf16.h>

#define G 200
#define NDIM 32
#define EDIM 19
#define KIN 51  // NDIM + EDIM

typedef unsigned short u16;
typedef unsigned int u32;
typedef unsigned long long u64;

typedef __attribute__((ext_vector_type(8))) short bfrag;   // 8 bf16 (4 VGPRs)
typedef __attribute__((ext_vector_type(4))) float ffrag;   // 4 fp32 acc

__device__ __forceinline__ float lrelu(float x){ return x > 0.f ? x : 0.01f*x; }
__device__ __forceinline__ u16 f2b(float x){ u32 u = __float_as_uint(x); return (u16)((u + 0x7fffu + ((u >> 16) & 1u)) >> 16); }
__device__ __forceinline__ float b2f(u16 x){ return __uint_as_float(((u32)x) << 16); }
// HW packed f32->bf16 RNE pair -- used ONLY inside edge_csr's MFMA-interleaved staging
__device__ __forceinline__ u32 f2b2(float a, float b){
  u32 r;
  asm("v_cvt_pk_bf16_f32 %0, %1, %2" : "=v"(r) : "v"(a), "v"(b));
  return r;
}

#define MFMA16(a, b, c) __builtin_amdgcn_mfma_f32_16x16x32_bf16(a, b, c, 0, 0, 0)

// ---------------- fused init: zero s_raw/denom/deg/l1 + nf->bf16 + all weight prep + bwt ----------------
__global__ void init_kernel(float* __restrict__ s_raw, float* __restrict__ denom,
                            int* __restrict__ deg, float* __restrict__ l1,
                            const float* __restrict__ nf, u16* __restrict__ nfb,
                            const float* __restrict__ We1, const float* __restrict__ Wn,
                            const float* __restrict__ Wet, const float* __restrict__ Wih,
                            const float* __restrict__ Whh,
                            const float* __restrict__ be1, const float* __restrict__ We2,
                            u16* __restrict__ Wbg, u16* __restrict__ Wnb, u16* __restrict__ Wet2,
                            u16* __restrict__ Wrz, u16* __restrict__ Winn, u16* __restrict__ Whn,
                            u32* __restrict__ bwt, int N){
  int i = blockIdx.x * 256 + threadIdx.x;
  if (i < N * G) s_raw[i] = 0.f;
  if (i < N){ denom[i] = 0.f; deg[i] = 0; l1[i] = 0.f; }
  if (i < N * NDIM) nfb[i] = f2b(nf[i]);
  if (i < 208){
    float bv = (i < G) ? be1[i] : 0.f;
    float wv = (i < G) ? We2[G + i] : 0.f;
    bwt[i] = (u32)f2b(bv) | ((u32)f2b(wv) << 16);
  }

  int idx = i;
  const int s0 = 208 * 64, s1 = 256 * 64, s2 = 208 * 224, s3 = 2 * 208 * 416, s4 = 208 * 224, s5 = 208 * 224;
  if (idx < s0){
    int r = idx >> 6, k = idx & 63;
    Wbg[idx] = f2b((r < G && k < KIN) ? We1[r * KIN + k] : 0.f);
    return;
  }
  idx -= s0;
  if (idx < s1){
    int r = idx >> 6, k = idx & 63;
    Wnb[idx] = f2b((r < G && k < NDIM) ? Wn[r * NDIM + k] : 0.f);
    return;
  }
  idx -= s1;
  if (idx < s2){
    int r = idx / 224, k = idx % 224;
    Wet2[idx] = f2b((r < G && k < G) ? Wet[r * G + k] : 0.f);
    return;
  }
  idx -= s2;
  if (idx < s3){
    int g = idx / (208 * 416), rem = idx % (208 * 416);
    int r = rem / 416, k = rem % 416;
    float v = 0.f;
    if (r < G){
      int row = g * G + r;
      if (k < G) v = Wih[row * G + k];
      else if (k >= 208 && k < 408) v = Whh[row * G + (k - 208)];
    }
    Wrz[idx] = f2b(v);
    return;
  }
  idx -= s3;
  if (idx < s4){
    int r = idx / 224, k = idx % 224;
    Winn[idx] = f2b((r < G && k < G) ? Wih[(2 * G + r) * G + k] : 0.f);
    return;
  }
  idx -= s4;
  if (idx < s5){
    int r = idx / 224, kk = idx % 224;
    Whn[idx] = f2b((r < G && kk >= 16 && kk < 216) ? Whh[(2 * G + r) * G + (kk - 16)] : 0.f);
  }
}

// ---------------- degree histogram ----------------
__global__ void deghist_kernel(const int* __restrict__ dst, int* __restrict__ deg, int E){
  int e = blockIdx.x * 256 + threadIdx.x;
  if (e < E) atomicAdd(&deg[dst[e]], 1);
}

// ---------------- single-pass block scan, LDS-staged coalesced loads ----------------
__global__ __launch_bounds__(1024) void scan_kernel(const int* __restrict__ deg, int* __restrict__ offs,
                                                    int* __restrict__ cur, int N){
  __shared__ int sd[12800];
  __shared__ int wsums[16];
  const int C = 25;  // 1024*25 = 25600 >= N
  int tid = threadIdx.x;
  int lane = tid & 63, wid = tid >> 6;
  int val[C];
  for (int h = 0; h < 2; ++h){
    int base_h = h * 12800;
    for (int k = tid; k < 12800; k += 1024){
      int gi = base_h + k;
      sd[k] = (gi < N) ? deg[gi] : 0;
    }
    __syncthreads();
    if ((tid >> 9) == h){
      int t0 = (tid - h * 512) * C;
      #pragma unroll
      for (int i = 0; i < C; ++i) val[i] = sd[t0 + i];
    }
    __syncthreads();
  }
  int s = 0;
  #pragma unroll
  for (int i = 0; i < C; ++i){ int v = val[i]; val[i] = s; s += v; }
  int x = s;
  #pragma unroll
  for (int off = 1; off < 64; off <<= 1){
    int y = __shfl_up(x, off, 64);
    if (lane >= off) x += y;
  }
  if (lane == 63) wsums[wid] = x;
  __syncthreads();
  if (wid == 0){
    int w = (lane < 16) ? wsums[lane] : 0;
    #pragma unroll
    for (int off = 1; off < 16; off <<= 1){
      int y = __shfl_up(w, off, 64);
      if (lane >= off) w += y;
    }
    if (lane < 16) wsums[lane] = w;
  }
  __syncthreads();
  int excl = ((wid ? wsums[wid - 1] : 0) + x) - s;
  int base = tid * C;
  #pragma unroll
  for (int i = 0; i < C; ++i){
    int o = excl + val[i];
    if (base + i < N){ offs[base + i] = o; cur[base + i] = o; }
  }
  if (tid == 1023) offs[N] = excl + s;
}

// ---------------- scatter + pack: ONE aligned 64B record per edge ----------------
// record (u32[16]): [0]=dst [1]=src [2]=l1[dst] bits [3]=0 [4..15]=24 bf16 edge feats
__global__ void scatter_pack_kernel(const int* __restrict__ dst, const int* __restrict__ src,
                                    const float* __restrict__ ef, const float* __restrict__ l1,
                                    int* __restrict__ cur, u32* __restrict__ erec, int E){
  int e = blockIdx.x * 256 + threadIdx.x;
  if (e >= E) return;
  int d = dst[e];
  int pos = atomicAdd(&cur[d], 1);
  u32 w[16];
  w[0] = (u32)d; w[1] = (u32)src[e]; w[2] = __float_as_uint(l1[d]); w[3] = 0u;
  const float* ep = ef + (long)e * EDIM;
  #pragma unroll
  for (int j = 0; j < 9; ++j) w[4 + j] = (u32)f2b(ep[2 * j]) | ((u32)f2b(ep[2 * j + 1]) << 16);
  w[13] = (u32)f2b(ep[18]);
  w[14] = 0u; w[15] = 0u;
  uint4* dp = (uint4*)(erec + (size_t)pos * 16);
  dp[0] = make_uint4(w[0], w[1], w[2], w[3]);
  dp[1] = make_uint4(w[4], w[5], w[6], w[7]);
  dp[2] = make_uint4(w[8], w[9], w[10], w[11]);
  dp[3] = make_uint4(w[12], w[13], w[14], w[15]);
}

// ---------------- hv GEMM + fused l1 partials: hvb = bf16(lrelu(nf@Wn^T+bn)); l1 += We2[.]·hv ----------------
__global__ __launch_bounds__(256) void hvgemm_kernel(
    const float* __restrict__ nf, const u16* __restrict__ Wnb, const float* __restrict__ bn,
    const float* __restrict__ We2, u16* __restrict__ hvb, float* __restrict__ l1, int M)
{
  __shared__ __align__(16) u16 As[64][72];
  __shared__ __align__(16) u16 Ws[64][72];
  int tid = threadIdx.x;
  int m0 = blockIdx.y * 64, n0 = blockIdx.x * 64;
  int l = tid & 63, w = tid >> 6, quad = l >> 4, col = l & 15;

  for (int idx = tid; idx < 64 * 16; idx += 256){
    int r = idx >> 4, c4 = idx & 15;
    int row = m0 + r, k = c4 * 4;
    float4 v = make_float4(0.f,0.f,0.f,0.f);
    if (row < M && k < NDIM) v = *(const float4*)(nf + (long)row * NDIM + k);
    *(ushort4*)&As[r][c4 * 4] = make_ushort4(f2b(v.x), f2b(v.y), f2b(v.z), f2b(v.w));
  }
  for (int idx = tid; idx < 64 * 8; idx += 256){
    int r = idx >> 3, c = idx & 7;
    *(ulonglong2*)&Ws[r][c * 8] = *(const ulonglong2*)(Wnb + (long)(n0 + r) * 64 + c * 8);
  }
  __syncthreads();
  bfrag a0 = *(const bfrag*)&As[w * 16 + col][quad * 8];
  bfrag a1 = *(const bfrag*)&As[w * 16 + col][32 + quad * 8];
  ffrag acc[4];
  #pragma unroll
  for (int t = 0; t < 4; ++t){ acc[t].x = 0.f; acc[t].y = 0.f; acc[t].z = 0.f; acc[t].w = 0.f; }
  #pragma unroll
  for (int t = 0; t < 4; ++t){
    bfrag b0 = *(const bfrag*)&Ws[t * 16 + col][quad * 8];
    bfrag b1 = *(const bfrag*)&Ws[t * 16 + col][32 + quad * 8];
    acc[t] = MFMA16(a0, b0, acc[t]);
    acc[t] = MFMA16(a1, b1, acc[t]);
  }
  float lp[4] = {0.f, 0.f, 0.f, 0.f};
  #pragma unroll
  for (int t = 0; t < 4; ++t){
    int n = n0 + t * 16 + col;
    float bv = (n < G) ? bn[n] : 0.f;
    float wv = (n < G) ? We2[n] : 0.f;
    #pragma unroll
    for (int r = 0; r < 4; ++r){
      int row = m0 + w * 16 + quad * 4 + r;
      float v = lrelu(acc[t][r] + bv);
      lp[r] += wv * v;
      if (n < G && row < M) hvb[(long)row * G + n] = f2b(v);
    }
  }
  #pragma unroll
  for (int r = 0; r < 4; ++r){
    lp[r] += __shfl_xor(lp[r], 1, 16);
    lp[r] += __shfl_xor(lp[r], 2, 16);
    lp[r] += __shfl_xor(lp[r], 4, 16);
    lp[r] += __shfl_xor(lp[r], 8, 16);
  }
  if (col == 0){
    #pragma unroll
    for (int r = 0; r < 4; ++r){
      int row = m0 + w * 16 + quad * 4 + r;
      if (row < M) atomicAdd(&l1[row], lp[r]);
    }
  }
}

// ---------------- CSR edge kernel v11: stage stride 72->64 + XOR swizzle -> 6 blocks/CU ----------------
// stage row = 128B; byte_off ^= (row&7)<<4 on BOTH write and read (identical transform, bijective
// per row, preserves 8B/16B chunk contiguity). LDS ~27.1KB < 160/6 -> occupancy 10->12 waves/CU.
__device__ __forceinline__ u16* stg_ptr(u16* shm, int row, int byte_off){
  return (u16*)((char*)(shm + row * 64) + (byte_off ^ ((row & 7) << 4)));
}
__device__ __forceinline__ const u16* stg_cptr(const u16* shm, int row, int byte_off){
  return (const u16*)((const char*)(shm + row * 64) + (byte_off ^ ((row & 7) << 4)));
}

__global__ __launch_bounds__(128, 2) void edge_csr_kernel(
    const u16* __restrict__ nfb, const u32* __restrict__ erec, const int* __restrict__ offs,
    const u16* __restrict__ Wbg, const u32* __restrict__ bwt, const float* __restrict__ be2,
    float* __restrict__ s_raw, float* __restrict__ denom, int E)
{
  __shared__ __align__(128) u16 shm[208 * 64];  // stageT [208][64], swizzled
  __shared__ int segnode[64];
  __shared__ __align__(16) u16 exb[64];
  __shared__ __align__(8) unsigned char segb[64];
  __shared__ int Svar;

  int tid = threadIdx.x;
  int j0 = blockIdx.x * 64;
  int l = tid & 63, w = tid >> 6;        // w in {0,1}
  int quad = l >> 4, col = l & 15;
  int m0a = w * 32, m0b = w * 32 + 16;

  // ---- issue longest-latency chains first: src index -> nfb gather (HBM-random) ----
  int ja = j0 + m0a + col;
  int jb = j0 + m0b + col;
  bool va = ja < E, vb = jb < E;
  int sa = va ? (int)erec[(size_t)ja * 16 + 1] : 0;
  int sb = vb ? (int)erec[(size_t)jb * 16 + 1] : 0;
  bfrag a0a = {0,0,0,0,0,0,0,0}, a1a = {0,0,0,0,0,0,0,0};
  bfrag a0b = {0,0,0,0,0,0,0,0}, a1b = {0,0,0,0,0,0,0,0};
  if (va){
    a0a = *(const bfrag*)(nfb + (long)sa * NDIM + quad * 8);
    if (quad < 3) a1a = *(const bfrag*)((const u16*)erec + (size_t)ja * 32 + 8 + quad * 8);
  }
  if (vb){
    a0b = *(const bfrag*)(nfb + (long)sb * NDIM + quad * 8);
    if (quad < 3) a1b = *(const bfrag*)((const u16*)erec + (size_t)jb * 32 + 8 + quad * 8);
  }

  // ---- prefetch ALL B fragments + bias/weight words into registers (L2-hot burst) ----
  bfrag B0[13], B1[13];
  u32 bwp[13];
  #pragma unroll
  for (int t = 0; t < 13; ++t){
    B0[t] = *(const bfrag*)(Wbg + (t * 16 + col) * 64 + quad * 8);
    B1[t] = *(const bfrag*)(Wbg + (t * 16 + col) * 64 + 32 + quad * 8);
    bwp[t] = bwt[t * 16 + col];
  }

  // ---- meta: wave 0 only (overlaps the loads above) ----
  if (tid < 64){
    int j = j0 + tid;
    int valid = j < E;
    int n = valid ? (int)erec[(size_t)j * 16] : -1;
    int nn = (tid == 63 || j + 1 >= E) ? -2 : (int)erec[(size_t)(j + 1) * 16];
    int f1 = (valid && n != nn) ? 1 : 0;
    int f2 = 0;
    if (f1 && offs[n] >= j0 && offs[n + 1] <= j0 + 64) f2 = 1;
    u64 em = __ballot(f1 != 0);
    int seg = (int)__popcll(em & ((1ull << tid) - 1ull));
    segb[tid] = (unsigned char)seg;
    if (f1) segnode[seg] = (n << 1) | f2;
    if (tid == 0) Svar = (int)__popcll(em);
    *stg_ptr(shm, 200, tid * 2) = 0x3F80;  // ones row (row&7==0 -> swz 0)
  }

  // ---- phase 1: 13 he1 tiles x 2 strips, pure-register operands ----
  float pla[4] = {0.f, 0.f, 0.f, 0.f};
  float plb[4] = {0.f, 0.f, 0.f, 0.f};
  #pragma unroll
  for (int t = 0; t < 13; ++t){
    ffrag acca; acca.x = 0.f; acca.y = 0.f; acca.z = 0.f; acca.w = 0.f;
    ffrag accb; accb.x = 0.f; accb.y = 0.f; accb.z = 0.f; accb.w = 0.f;
    acca = MFMA16(a0a, B0[t], acca);
    acca = MFMA16(a1a, B1[t], acca);
    accb = MFMA16(a0b, B0[t], accb);
    accb = MFMA16(a1b, B1[t], accb);
    int g = t * 16 + col;
    u32 bw = bwp[t];
    float bv = b2f((u16)(bw & 0xFFFF)), wv = b2f((u16)(bw >> 16));
    float u0 = lrelu(acca.x + bv), u1 = lrelu(acca.y + bv);
    float u2 = lrelu(acca.z + bv), u3 = lrelu(acca.w + bv);
    pla[0] += wv * u0; pla[1] += wv * u1; pla[2] += wv * u2; pla[3] += wv * u3;
    float v0 = lrelu(accb.x + bv), v1 = lrelu(accb.y + bv);
    float v2 = lrelu(accb.z + bv), v3 = lrelu(accb.w + bv);
    plb[0] += wv * v0; plb[1] += wv * v1; plb[2] += wv * v2; plb[3] += wv * v3;
    if (g < G){
      *(uint2*)stg_ptr(shm, g, (m0a + quad * 4) * 2) = make_uint2(f2b2(u0, u1), f2b2(u2, u3));
      *(uint2*)stg_ptr(shm, g, (m0b + quad * 4) * 2) = make_uint2(f2b2(v0, v1), f2b2(v2, v3));
    }
  }
  #pragma unroll
  for (int r = 0; r < 4; ++r){
    pla[r] += __shfl_xor(pla[r], 1, 16);
    pla[r] += __shfl_xor(pla[r], 2, 16);
    pla[r] += __shfl_xor(pla[r], 4, 16);
    pla[r] += __shfl_xor(pla[r], 8, 16);
    plb[r] += __shfl_xor(plb[r], 1, 16);
    plb[r] += __shfl_xor(plb[r], 2, 16);
    plb[r] += __shfl_xor(plb[r], 4, 16);
    plb[r] += __shfl_xor(plb[r], 8, 16);
  }
  if (col == 0){
    #pragma unroll
    for (int r = 0; r < 4; ++r){
      int ea = m0a + quad * 4 + r;
      float exa = 0.f;
      if (j0 + ea < E){
        float l1v = __uint_as_float(erec[(size_t)(j0 + ea) * 16 + 2]);
        exa = __expf(lrelu(pla[r] + l1v + be2[0]));
      }
      exb[ea] = f2b(exa);
      int eb = m0b + quad * 4 + r;
      float exv = 0.f;
      if (j0 + eb < E){
        float l1v = __uint_as_float(erec[(size_t)(j0 + eb) * 16 + 2]);
        exv = __expf(lrelu(plb[r] + l1v + be2[0]));
      }
      exb[eb] = f2b(exv);
    }
  }
  __syncthreads();  // the ONLY barrier

  // ---- phase 2: MFMA segment reduction (tiles 0..6 -> wave 0, 7..12 -> wave 1) ----
  int S = Svar;
  for (int mt = 0; mt * 16 < S; ++mt){
    int m = mt * 16 + col;
    u64 sb0 = *(const u64*)&segb[quad * 8];
    u64 sb1 = *(const u64*)&segb[32 + quad * 8];
    ulonglong2 ew0 = *(const ulonglong2*)&exb[quad * 8];
    ulonglong2 ew1 = *(const ulonglong2*)&exb[32 + quad * 8];
    bfrag A0, A1;
    #pragma unroll
    for (int jj = 0; jj < 8; ++jj){
      int s0i = (int)((sb0 >> (8 * jj)) & 0xFF);
      int s1i = (int)((sb1 >> (8 * jj)) & 0xFF);
      u64 w0 = (jj < 4) ? ew0.x : ew0.y;
      u64 w1 = (jj < 4) ? ew1.x : ew1.y;
      u16 e0 = (u16)(w0 >> (16 * (jj & 3)));
      u16 e1 = (u16)(w1 >> (16 * (jj & 3)));
      A0[jj] = (s0i == m) ? (short)e0 : (short)0;
      A1[jj] = (s1i == m) ? (short)e1 : (short)0;
    }
    int t0 = (w == 0) ? 0 : 7;
    int cnt = (w == 0) ? 7 : 6;
    for (int i = 0; i < cnt; ++i){
      int t = t0 + i;
      int row = t * 16 + col;
      bfrag b0 = *(const bfrag*)stg_cptr(shm, row, quad * 16);
      bfrag b1 = *(const bfrag*)stg_cptr(shm, row, 64 + quad * 16);
      ffrag acc; acc.x = 0.f; acc.y = 0.f; acc.z = 0.f; acc.w = 0.f;
      acc = MFMA16(A0, b0, acc);
      acc = MFMA16(A1, b1, acc);
      int g = row;
      #pragma unroll
      for (int r = 0; r < 4; ++r){
        int seg = mt * 16 + quad * 4 + r;
        if (seg < S && g <= 200){
          int enc = segnode[seg];
          int nd = enc >> 1;
          float v = acc[r];
          float* pd = (g < G) ? (s_raw + (long)nd * G + g) : (denom + nd);
          if (enc & 1) *pd = v; else atomicAdd(pd, v);
        }
      }
    }
  }
}

// ---------------- fused ctx + GRU kernel v4: 16 rows/block, 2 waves splitting column tiles ----------------
// v2 was grid-starved (782 blocks -> ~6 waves/CU = 15% occ). 16-row blocks double the grid to 1563;
// the 2 waves split the 13 output column-tiles (7/6) in both phases -> ~12 waves/CU.
#define XST 420
__global__ __launch_bounds__(128, 2) void ctxgru_kernel(
    const float* __restrict__ s_raw, const u16* __restrict__ hvb, const float* __restrict__ denom,
    const u16* __restrict__ Wet2, const u16* __restrict__ Wrz,
    const u16* __restrict__ Winn, const u16* __restrict__ Whn,
    const float* __restrict__ bet, const float* __restrict__ b_ih, const float* __restrict__ b_hh,
    float* __restrict__ out, int M)
{
  __shared__ __align__(16) u16 X[16 * XST];
  __shared__ float invds[16];
  int tid = threadIdx.x;
  int m0 = blockIdx.x * 16;

  if (tid < 16){
    float dn = (m0 + tid < M) ? denom[m0 + tid] : 0.f;
    invds[tid] = dn > 0.f ? 1.f / dn : 0.f;
  }
  __syncthreads();

  for (int idx = tid; idx < 16 * 50; idx += 128){
    int r = idx / 50, c = idx % 50;
    int row = m0 + r;
    float4 v = make_float4(0.f,0.f,0.f,0.f);
    ushort4 h = make_ushort4(0,0,0,0);
    if (row < M){
      v = *(const float4*)(s_raw + (long)row * G + c * 4);
      h = *(const ushort4*)(hvb + (long)row * G + c * 4);
    }
    float iv = invds[r];
    *(ushort4*)&X[r * XST + c * 4] = make_ushort4(f2b(v.x*iv), f2b(v.y*iv), f2b(v.z*iv), f2b(v.w*iv));
    *(ushort4*)&X[r * XST + 208 + c * 4] = h;
  }
  for (int idx = tid; idx < 16 * 4; idx += 128){
    int r = idx / 4, q = idx % 4;
    int base = (q < 2) ? (200 + q * 4) : (408 + (q - 2) * 4);
    *(ushort4*)&X[r * XST + base] = make_ushort4(0,0,0,0);
  }
  __syncthreads();

  int l = tid & 63, w = tid >> 6, quad = l >> 4, col = l & 15;
  int st0 = (w == 0) ? 0 : 7;
  int stn = (w == 0) ? 7 : 6;

  // ---- phase 1: ctx (wave w computes its 7/6 column tiles for all 16 rows) ----
  bfrag a1[7];
  #pragma unroll
  for (int j = 0; j < 7; ++j) a1[j] = *(const bfrag*)&X[col * XST + j * 32 + quad * 8];

  for (int ii = 0; ii < stn; ++ii){
    int st = st0 + ii;
    int n = st * 16 + col;
    ffrag acc; acc.x = 0.f; acc.y = 0.f; acc.z = 0.f; acc.w = 0.f;
    #pragma unroll
    for (int j = 0; j < 7; ++j){
      bfrag b = *(const bfrag*)(Wet2 + (long)n * 224 + j * 32 + quad * 8);
      acc = MFMA16(a1[j], b, acc);
    }
    if (n < G){
      float bv = bet[n];
      #pragma unroll
      for (int r = 0; r < 4; ++r){
        int lr = quad * 4 + r;
        float gate = invds[lr] > 0.f ? 1.f : 0.f;
        float v = acc[r] + gate * bv;
        v = (v > 0.f) ? v : (__expf(v) - 1.f);
        X[lr * XST + n] = f2b(v);
      }
    }
  }
  __syncthreads();

  // ---- phase 2: gates + GRU (same 7/6 split) ----
  bfrag a2[13];
  #pragma unroll
  for (int j = 0; j < 13; ++j) a2[j] = *(const bfrag*)&X[col * XST + j * 32 + quad * 8];

  for (int ii = 0; ii < stn; ++ii){
    int st = st0 + ii;
    int n = st * 16 + col;
    ffrag ar, az, ai, ah;
    ar.x=ar.y=ar.z=ar.w=0.f; az.x=az.y=az.z=az.w=0.f;
    ai.x=ai.y=ai.z=ai.w=0.f; ah.x=ah.y=ah.z=ah.w=0.f;
    #pragma unroll
    for (int j = 0; j < 13; ++j){
      bfrag br_ = *(const bfrag*)(Wrz + (long)n * 416 + j * 32 + quad * 8);
      ar = MFMA16(a2[j], br_, ar);
      bfrag bz_ = *(const bfrag*)(Wrz + (long)(208 + n) * 416 + j * 32 + quad * 8);
      az = MFMA16(a2[j], bz_, az);
    }
    #pragma unroll
    for (int j = 0; j < 7; ++j){
      bfrag bi_ = *(const bfrag*)(Winn + (long)n * 224 + j * 32 + quad * 8);
      ai = MFMA16(a2[j], bi_, ai);
      bfrag bh_ = *(const bfrag*)(Whn + (long)n * 224 + j * 32 + quad * 8);
      ah = MFMA16(a2[j + 6], bh_, ah);
    }
    if (n < G){
      float br = b_ih[n] + b_hh[n];
      float bz = b_ih[G + n] + b_hh[G + n];
      float bi = b_ih[2 * G + n];
      float bh = b_hh[2 * G + n];
      #pragma unroll
      for (int r = 0; r < 4; ++r){
        int lr = quad * 4 + r;
        int row = m0 + lr;
        if (row < M){
          float rg = 1.f / (1.f + __expf(-(ar[r] + br)));
          float zg = 1.f / (1.f + __expf(-(az[r] + bz)));
          float ng = tanhf(ai[r] + bi + rg * (ah[r] + bh));
          float hvv = b2f(X[lr * XST + 208 + n]);
          float h = (1.f - zg) * ng + zg * hvv;
          out[(long)row * G + n] = h > 0.f ? h : 0.f;
        }
      }
    }
  }
}

extern "C" void kernel_launch(void* const* d_in, const int* in_sizes, int n_in,
                              void* d_out, int out_size, void* d_ws, size_t ws_size,
                              hipStream_t stream)
{
  const float* nf   = (const float*)d_in[0];
  const float* ef   = (const float*)d_in[1];
  const int*   src  = (const int*)d_in[2];
  const int*   dst  = (const int*)d_in[3];
  const float* Wn   = (const float*)d_in[4];
  const float* bn   = (const float*)d_in[5];
  const float* We1  = (const float*)d_in[6];
  const float* be1  = (const float*)d_in[7];
  const float* We2  = (const float*)d_in[8];
  const float* be2  = (const float*)d_in[9];
  const float* Wet  = (const float*)d_in[10];
  const float* bet  = (const float*)d_in[11];
  const float* W_ih = (const float*)d_in[12];
  const float* b_ih = (const float*)d_in[13];
  const float* W_hh = (const float*)d_in[14];
  const float* b_hh = (const float*)d_in[15];
  int N = in_sizes[0] / NDIM;   // 25000
  int E = in_sizes[2];          // 500000
  float* out = (float*)d_out;

  char* p = (char*)d_ws;
  auto alloc = [&](size_t b){ char* r = p; p += (b + 255) & ~(size_t)255; return r; };
  u16*   hvb   = (u16*)  alloc((size_t)N * G * 2);
  float* s_raw = (float*)alloc((size_t)N * G * 4);
  float* denom = (float*)alloc((size_t)N * 4);
  int*   deg   = (int*)  alloc((size_t)N * 4);
  int*   offs  = (int*)  alloc((size_t)(N + 1) * 4);
  int*   cur   = (int*)  alloc((size_t)N * 4);
  u32*   erec  = (u32*)  alloc((size_t)E * 64);
  u16*   nfb   = (u16*)  alloc((size_t)N * NDIM * 2);
  float* l1    = (float*)alloc((size_t)N * 4);
  u16*   Wbg   = (u16*)  alloc((size_t)208 * 64 * 2);
  u16*   Wnb   = (u16*)  alloc((size_t)256 * 64 * 2);
  u16*   Wet2  = (u16*)  alloc((size_t)208 * 224 * 2);
  u16*   Wrz   = (u16*)  alloc((size_t)2 * 208 * 416 * 2);
  u16*   Winn  = (u16*)  alloc((size_t)208 * 224 * 2);
  u16*   Whn   = (u16*)  alloc((size_t)208 * 224 * 2);
  u32*   bwt   = (u32*)  alloc((size_t)208 * 4);

  int eb = (E + 255) / 256;
  int mb = (N + 63) / 64;
  int mb3 = (N + 15) / 16;

  init_kernel<<<dim3((N * G + 255) / 256), dim3(256), 0, stream>>>(
      s_raw, denom, deg, l1, nf, nfb, We1, Wn, Wet, W_ih, W_hh, be1, We2,
      Wbg, Wnb, Wet2, Wrz, Winn, Whn, bwt, N);
  deghist_kernel<<<dim3(eb), dim3(256), 0, stream>>>(dst, deg, E);
  scan_kernel<<<dim3(1), dim3(1024), 0, stream>>>(deg, offs, cur, N);
  hvgemm_kernel<<<dim3(4, mb), dim3(256), 0, stream>>>(nf, Wnb, bn, We2, hvb, l1, N);
  scatter_pack_kernel<<<dim3(eb), dim3(256), 0, stream>>>(dst, src, ef, l1, cur, erec, E);
  edge_csr_kernel<<<dim3((E + 63) / 64), dim3(128), 0, stream>>>(nfb, erec, offs,
                                                                 Wbg, bwt, be2, s_raw, denom, E);
  ctxgru_kernel<<<dim3(mb3), dim3(128), 0, stream>>>(s_raw, hvb, denom, Wet2, Wrz, Winn, Whn,
                                                     bet, b_ih, b_hh, out, N);
}

// Round 11
// 400.822 us; speedup vs baseline: 1.0295x; 1.0295x over previous
//
#include <hip/hip_runtime.h>
#include <hip/hip_bf16.h>

#define G 200
#define NDIM 32
#define EDIM 19
#define KIN 51  // NDIM + EDIM

typedef unsigned short u16;
typedef unsigned int u32;
typedef unsigned long long u64;

typedef __attribute__((ext_vector_type(8))) short bfrag;   // 8 bf16 (4 VGPRs)
typedef __attribute__((ext_vector_type(4))) float ffrag;   // 4 fp32 acc

__device__ __forceinline__ float lrelu(float x){ return x > 0.f ? x : 0.01f*x; }
__device__ __forceinline__ u16 f2b(float x){ u32 u = __float_as_uint(x); return (u16)((u + 0x7fffu + ((u >> 16) & 1u)) >> 16); }
__device__ __forceinline__ float b2f(u16 x){ return __uint_as_float(((u32)x) << 16); }
// HW packed f32->bf16 RNE pair -- used ONLY inside edge_csr's MFMA-interleaved staging
__device__ __forceinline__ u32 f2b2(float a, float b){
  u32 r;
  asm("v_cvt_pk_bf16_f32 %0, %1, %2" : "=v"(r) : "v"(a), "v"(b));
  return r;
}

#define MFMA16(a, b, c) __builtin_amdgcn_mfma_f32_16x16x32_bf16(a, b, c, 0, 0, 0)

// ---------------- fused init: zero s_raw/denom/deg/l1 + nf->bf16 + all weight prep + bwt ----------------
__global__ void init_kernel(float* __restrict__ s_raw, float* __restrict__ denom,
                            int* __restrict__ deg, float* __restrict__ l1,
                            const float* __restrict__ nf, u16* __restrict__ nfb,
                            const float* __restrict__ We1, const float* __restrict__ Wn,
                            const float* __restrict__ Wet, const float* __restrict__ Wih,
                            const float* __restrict__ Whh,
                            const float* __restrict__ be1, const float* __restrict__ We2,
                            u16* __restrict__ Wbg, u16* __restrict__ Wnb, u16* __restrict__ Wet2,
                            u16* __restrict__ Wrz, u16* __restrict__ Winn, u16* __restrict__ Whn,
                            u32* __restrict__ bwt, int N){
  int i = blockIdx.x * 256 + threadIdx.x;
  if (i < N * G) s_raw[i] = 0.f;
  if (i < N){ denom[i] = 0.f; deg[i] = 0; l1[i] = 0.f; }
  if (i < N * NDIM) nfb[i] = f2b(nf[i]);
  if (i < 208){
    float bv = (i < G) ? be1[i] : 0.f;
    float wv = (i < G) ? We2[G + i] : 0.f;
    bwt[i] = (u32)f2b(bv) | ((u32)f2b(wv) << 16);
  }

  int idx = i;
  const int s0 = 208 * 64, s1 = 256 * 64, s2 = 208 * 224, s3 = 2 * 208 * 416, s4 = 208 * 224, s5 = 208 * 224;
  if (idx < s0){
    int r = idx >> 6, k = idx & 63;
    Wbg[idx] = f2b((r < G && k < KIN) ? We1[r * KIN + k] : 0.f);
    return;
  }
  idx -= s0;
  if (idx < s1){
    int r = idx >> 6, k = idx & 63;
    Wnb[idx] = f2b((r < G && k < NDIM) ? Wn[r * NDIM + k] : 0.f);
    return;
  }
  idx -= s1;
  if (idx < s2){
    int r = idx / 224, k = idx % 224;
    Wet2[idx] = f2b((r < G && k < G) ? Wet[r * G + k] : 0.f);
    return;
  }
  idx -= s2;
  if (idx < s3){
    int g = idx / (208 * 416), rem = idx % (208 * 416);
    int r = rem / 416, k = rem % 416;
    float v = 0.f;
    if (r < G){
      int row = g * G + r;
      if (k < G) v = Wih[row * G + k];
      else if (k >= 208 && k < 408) v = Whh[row * G + (k - 208)];
    }
    Wrz[idx] = f2b(v);
    return;
  }
  idx -= s3;
  if (idx < s4){
    int r = idx / 224, k = idx % 224;
    Winn[idx] = f2b((r < G && k < G) ? Wih[(2 * G + r) * G + k] : 0.f);
    return;
  }
  idx -= s4;
  if (idx < s5){
    int r = idx / 224, kk = idx % 224;
    Whn[idx] = f2b((r < G && kk >= 16 && kk < 216) ? Whh[(2 * G + r) * G + (kk - 16)] : 0.f);
  }
}

// ---------------- degree histogram ----------------
__global__ void deghist_kernel(const int* __restrict__ dst, int* __restrict__ deg, int E){
  int e = blockIdx.x * 256 + threadIdx.x;
  if (e < E) atomicAdd(&deg[dst[e]], 1);
}

// ---------------- single-pass block scan, LDS-staged coalesced loads ----------------
__global__ __launch_bounds__(1024) void scan_kernel(const int* __restrict__ deg, int* __restrict__ offs,
                                                    int* __restrict__ cur, int N){
  __shared__ int sd[12800];
  __shared__ int wsums[16];
  const int C = 25;  // 1024*25 = 25600 >= N
  int tid = threadIdx.x;
  int lane = tid & 63, wid = tid >> 6;
  int val[C];
  for (int h = 0; h < 2; ++h){
    int base_h = h * 12800;
    for (int k = tid; k < 12800; k += 1024){
      int gi = base_h + k;
      sd[k] = (gi < N) ? deg[gi] : 0;
    }
    __syncthreads();
    if ((tid >> 9) == h){
      int t0 = (tid - h * 512) * C;
      #pragma unroll
      for (int i = 0; i < C; ++i) val[i] = sd[t0 + i];
    }
    __syncthreads();
  }
  int s = 0;
  #pragma unroll
  for (int i = 0; i < C; ++i){ int v = val[i]; val[i] = s; s += v; }
  int x = s;
  #pragma unroll
  for (int off = 1; off < 64; off <<= 1){
    int y = __shfl_up(x, off, 64);
    if (lane >= off) x += y;
  }
  if (lane == 63) wsums[wid] = x;
  __syncthreads();
  if (wid == 0){
    int w = (lane < 16) ? wsums[lane] : 0;
    #pragma unroll
    for (int off = 1; off < 16; off <<= 1){
      int y = __shfl_up(w, off, 64);
      if (lane >= off) w += y;
    }
    if (lane < 16) wsums[lane] = w;
  }
  __syncthreads();
  int excl = ((wid ? wsums[wid - 1] : 0) + x) - s;
  int base = tid * C;
  #pragma unroll
  for (int i = 0; i < C; ++i){
    int o = excl + val[i];
    if (base + i < N){ offs[base + i] = o; cur[base + i] = o; }
  }
  if (tid == 1023) offs[N] = excl + s;
}

// ---------------- scatter + pack: ONE aligned 64B record per edge ----------------
// record (u32[16]): [0]=dst [1]=src [2]=l1[dst] bits [3]=0 [4..15]=24 bf16 edge feats
__global__ void scatter_pack_kernel(const int* __restrict__ dst, const int* __restrict__ src,
                                    const float* __restrict__ ef, const float* __restrict__ l1,
                                    int* __restrict__ cur, u32* __restrict__ erec, int E){
  int e = blockIdx.x * 256 + threadIdx.x;
  if (e >= E) return;
  int d = dst[e];
  int pos = atomicAdd(&cur[d], 1);
  u32 w[16];
  w[0] = (u32)d; w[1] = (u32)src[e]; w[2] = __float_as_uint(l1[d]); w[3] = 0u;
  const float* ep = ef + (long)e * EDIM;
  #pragma unroll
  for (int j = 0; j < 9; ++j) w[4 + j] = (u32)f2b(ep[2 * j]) | ((u32)f2b(ep[2 * j + 1]) << 16);
  w[13] = (u32)f2b(ep[18]);
  w[14] = 0u; w[15] = 0u;
  uint4* dp = (uint4*)(erec + (size_t)pos * 16);
  dp[0] = make_uint4(w[0], w[1], w[2], w[3]);
  dp[1] = make_uint4(w[4], w[5], w[6], w[7]);
  dp[2] = make_uint4(w[8], w[9], w[10], w[11]);
  dp[3] = make_uint4(w[12], w[13], w[14], w[15]);
}

// ---------------- hv GEMM + fused l1 partials: hvb = bf16(lrelu(nf@Wn^T+bn)); l1 += We2[.]·hv ----------------
__global__ __launch_bounds__(256) void hvgemm_kernel(
    const float* __restrict__ nf, const u16* __restrict__ Wnb, const float* __restrict__ bn,
    const float* __restrict__ We2, u16* __restrict__ hvb, float* __restrict__ l1, int M)
{
  __shared__ __align__(16) u16 As[64][72];
  __shared__ __align__(16) u16 Ws[64][72];
  int tid = threadIdx.x;
  int m0 = blockIdx.y * 64, n0 = blockIdx.x * 64;
  int l = tid & 63, w = tid >> 6, quad = l >> 4, col = l & 15;

  for (int idx = tid; idx < 64 * 16; idx += 256){
    int r = idx >> 4, c4 = idx & 15;
    int row = m0 + r, k = c4 * 4;
    float4 v = make_float4(0.f,0.f,0.f,0.f);
    if (row < M && k < NDIM) v = *(const float4*)(nf + (long)row * NDIM + k);
    *(ushort4*)&As[r][c4 * 4] = make_ushort4(f2b(v.x), f2b(v.y), f2b(v.z), f2b(v.w));
  }
  for (int idx = tid; idx < 64 * 8; idx += 256){
    int r = idx >> 3, c = idx & 7;
    *(ulonglong2*)&Ws[r][c * 8] = *(const ulonglong2*)(Wnb + (long)(n0 + r) * 64 + c * 8);
  }
  __syncthreads();
  bfrag a0 = *(const bfrag*)&As[w * 16 + col][quad * 8];
  bfrag a1 = *(const bfrag*)&As[w * 16 + col][32 + quad * 8];
  ffrag acc[4];
  #pragma unroll
  for (int t = 0; t < 4; ++t){ acc[t].x = 0.f; acc[t].y = 0.f; acc[t].z = 0.f; acc[t].w = 0.f; }
  #pragma unroll
  for (int t = 0; t < 4; ++t){
    bfrag b0 = *(const bfrag*)&Ws[t * 16 + col][quad * 8];
    bfrag b1 = *(const bfrag*)&Ws[t * 16 + col][32 + quad * 8];
    acc[t] = MFMA16(a0, b0, acc[t]);
    acc[t] = MFMA16(a1, b1, acc[t]);
  }
  float lp[4] = {0.f, 0.f, 0.f, 0.f};
  #pragma unroll
  for (int t = 0; t < 4; ++t){
    int n = n0 + t * 16 + col;
    float bv = (n < G) ? bn[n] : 0.f;
    float wv = (n < G) ? We2[n] : 0.f;
    #pragma unroll
    for (int r = 0; r < 4; ++r){
      int row = m0 + w * 16 + quad * 4 + r;
      float v = lrelu(acc[t][r] + bv);
      lp[r] += wv * v;
      if (n < G && row < M) hvb[(long)row * G + n] = f2b(v);
    }
  }
  #pragma unroll
  for (int r = 0; r < 4; ++r){
    lp[r] += __shfl_xor(lp[r], 1, 16);
    lp[r] += __shfl_xor(lp[r], 2, 16);
    lp[r] += __shfl_xor(lp[r], 4, 16);
    lp[r] += __shfl_xor(lp[r], 8, 16);
  }
  if (col == 0){
    #pragma unroll
    for (int r = 0; r < 4; ++r){
      int row = m0 + w * 16 + quad * 4 + r;
      if (row < M) atomicAdd(&l1[row], lp[r]);
    }
  }
}

// ---------------- CSR edge kernel v10 (REVERTED from v11): stride-72 stage, no swizzle ----------------
// v11 (stride-64 + XOR swizzle) regressed 107->130us: 6th block still didn't fit (27136*6 > 160KB
// usable), VGPR 76->92 and extra addr VALU in the hot loop. v10 is the best-measured state.
#define SST 72
__global__ __launch_bounds__(128, 2) void edge_csr_kernel(
    const u16* __restrict__ nfb, const u32* __restrict__ erec, const int* __restrict__ offs,
    const u16* __restrict__ Wbg, const u32* __restrict__ bwt, const float* __restrict__ be2,
    float* __restrict__ s_raw, float* __restrict__ denom, int E)
{
  __shared__ __align__(16) u16 shm[208 * SST];  // stageT [208][72]
  __shared__ int segnode[64];
  __shared__ __align__(16) u16 exb[64];
  __shared__ __align__(8) unsigned char segb[64];
  __shared__ int Svar;

  int tid = threadIdx.x;
  int j0 = blockIdx.x * 64;
  int l = tid & 63, w = tid >> 6;        // w in {0,1}
  int quad = l >> 4, col = l & 15;
  int m0a = w * 32, m0b = w * 32 + 16;

  // ---- issue longest-latency chains first: src index -> nfb gather (HBM-random) ----
  int ja = j0 + m0a + col;
  int jb = j0 + m0b + col;
  bool va = ja < E, vb = jb < E;
  int sa = va ? (int)erec[(size_t)ja * 16 + 1] : 0;
  int sb = vb ? (int)erec[(size_t)jb * 16 + 1] : 0;
  bfrag a0a = {0,0,0,0,0,0,0,0}, a1a = {0,0,0,0,0,0,0,0};
  bfrag a0b = {0,0,0,0,0,0,0,0}, a1b = {0,0,0,0,0,0,0,0};
  if (va){
    a0a = *(const bfrag*)(nfb + (long)sa * NDIM + quad * 8);
    if (quad < 3) a1a = *(const bfrag*)((const u16*)erec + (size_t)ja * 32 + 8 + quad * 8);
  }
  if (vb){
    a0b = *(const bfrag*)(nfb + (long)sb * NDIM + quad * 8);
    if (quad < 3) a1b = *(const bfrag*)((const u16*)erec + (size_t)jb * 32 + 8 + quad * 8);
  }

  // ---- prefetch ALL B fragments + bias/weight words into registers (L2-hot burst) ----
  bfrag B0[13], B1[13];
  u32 bwp[13];
  #pragma unroll
  for (int t = 0; t < 13; ++t){
    B0[t] = *(const bfrag*)(Wbg + (t * 16 + col) * 64 + quad * 8);
    B1[t] = *(const bfrag*)(Wbg + (t * 16 + col) * 64 + 32 + quad * 8);
    bwp[t] = bwt[t * 16 + col];
  }

  // ---- meta: wave 0 only (overlaps the loads above) ----
  if (tid < 64){
    int j = j0 + tid;
    int valid = j < E;
    int n = valid ? (int)erec[(size_t)j * 16] : -1;
    int nn = (tid == 63 || j + 1 >= E) ? -2 : (int)erec[(size_t)(j + 1) * 16];
    int f1 = (valid && n != nn) ? 1 : 0;
    int f2 = 0;
    if (f1 && offs[n] >= j0 && offs[n + 1] <= j0 + 64) f2 = 1;
    u64 em = __ballot(f1 != 0);
    int seg = (int)__popcll(em & ((1ull << tid) - 1ull));
    segb[tid] = (unsigned char)seg;
    if (f1) segnode[seg] = (n << 1) | f2;
    if (tid == 0) Svar = (int)__popcll(em);
    shm[200 * SST + tid] = 0x3F80;  // ones row (for denom)
  }

  // ---- phase 1: 13 he1 tiles x 2 strips, pure-register operands ----
  float pla[4] = {0.f, 0.f, 0.f, 0.f};
  float plb[4] = {0.f, 0.f, 0.f, 0.f};
  #pragma unroll
  for (int t = 0; t < 13; ++t){
    ffrag acca; acca.x = 0.f; acca.y = 0.f; acca.z = 0.f; acca.w = 0.f;
    ffrag accb; accb.x = 0.f; accb.y = 0.f; accb.z = 0.f; accb.w = 0.f;
    acca = MFMA16(a0a, B0[t], acca);
    acca = MFMA16(a1a, B1[t], acca);
    accb = MFMA16(a0b, B0[t], accb);
    accb = MFMA16(a1b, B1[t], accb);
    int g = t * 16 + col;
    u32 bw = bwp[t];
    float bv = b2f((u16)(bw & 0xFFFF)), wv = b2f((u16)(bw >> 16));
    float u0 = lrelu(acca.x + bv), u1 = lrelu(acca.y + bv);
    float u2 = lrelu(acca.z + bv), u3 = lrelu(acca.w + bv);
    pla[0] += wv * u0; pla[1] += wv * u1; pla[2] += wv * u2; pla[3] += wv * u3;
    float v0 = lrelu(accb.x + bv), v1 = lrelu(accb.y + bv);
    float v2 = lrelu(accb.z + bv), v3 = lrelu(accb.w + bv);
    plb[0] += wv * v0; plb[1] += wv * v1; plb[2] += wv * v2; plb[3] += wv * v3;
    if (g < G){
      *(uint2*)&shm[g * SST + m0a + quad * 4] = make_uint2(f2b2(u0, u1), f2b2(u2, u3));
      *(uint2*)&shm[g * SST + m0b + quad * 4] = make_uint2(f2b2(v0, v1), f2b2(v2, v3));
    }
  }
  #pragma unroll
  for (int r = 0; r < 4; ++r){
    pla[r] += __shfl_xor(pla[r], 1, 16);
    pla[r] += __shfl_xor(pla[r], 2, 16);
    pla[r] += __shfl_xor(pla[r], 4, 16);
    pla[r] += __shfl_xor(pla[r], 8, 16);
    plb[r] += __shfl_xor(plb[r], 1, 16);
    plb[r] += __shfl_xor(plb[r], 2, 16);
    plb[r] += __shfl_xor(plb[r], 4, 16);
    plb[r] += __shfl_xor(plb[r], 8, 16);
  }
  if (col == 0){
    #pragma unroll
    for (int r = 0; r < 4; ++r){
      int ea = m0a + quad * 4 + r;
      float exa = 0.f;
      if (j0 + ea < E){
        float l1v = __uint_as_float(erec[(size_t)(j0 + ea) * 16 + 2]);
        exa = __expf(lrelu(pla[r] + l1v + be2[0]));
      }
      exb[ea] = f2b(exa);
      int eb = m0b + quad * 4 + r;
      float exv = 0.f;
      if (j0 + eb < E){
        float l1v = __uint_as_float(erec[(size_t)(j0 + eb) * 16 + 2]);
        exv = __expf(lrelu(plb[r] + l1v + be2[0]));
      }
      exb[eb] = f2b(exv);
    }
  }
  __syncthreads();  // the ONLY barrier

  // ---- phase 2: MFMA segment reduction (tiles 0..6 -> wave 0, 7..12 -> wave 1) ----
  int S = Svar;
  for (int mt = 0; mt * 16 < S; ++mt){
    int m = mt * 16 + col;
    u64 sb0 = *(const u64*)&segb[quad * 8];
    u64 sb1 = *(const u64*)&segb[32 + quad * 8];
    ulonglong2 ew0 = *(const ulonglong2*)&exb[quad * 8];
    ulonglong2 ew1 = *(const ulonglong2*)&exb[32 + quad * 8];
    bfrag A0, A1;
    #pragma unroll
    for (int jj = 0; jj < 8; ++jj){
      int s0i = (int)((sb0 >> (8 * jj)) & 0xFF);
      int s1i = (int)((sb1 >> (8 * jj)) & 0xFF);
      u64 w0 = (jj < 4) ? ew0.x : ew0.y;
      u64 w1 = (jj < 4) ? ew1.x : ew1.y;
      u16 e0 = (u16)(w0 >> (16 * (jj & 3)));
      u16 e1 = (u16)(w1 >> (16 * (jj & 3)));
      A0[jj] = (s0i == m) ? (short)e0 : (short)0;
      A1[jj] = (s1i == m) ? (short)e1 : (short)0;
    }
    int t0 = (w == 0) ? 0 : 7;
    int cnt = (w == 0) ? 7 : 6;
    for (int i = 0; i < cnt; ++i){
      int t = t0 + i;
      bfrag b0 = *(const bfrag*)&shm[(t * 16 + col) * SST + quad * 8];
      bfrag b1 = *(const bfrag*)&shm[(t * 16 + col) * SST + 32 + quad * 8];
      ffrag acc; acc.x = 0.f; acc.y = 0.f; acc.z = 0.f; acc.w = 0.f;
      acc = MFMA16(A0, b0, acc);
      acc = MFMA16(A1, b1, acc);
      int g = t * 16 + col;
      #pragma unroll
      for (int r = 0; r < 4; ++r){
        int seg = mt * 16 + quad * 4 + r;
        if (seg < S && g <= 200){
          int enc = segnode[seg];
          int nd = enc >> 1;
          float v = acc[r];
          float* pd = (g < G) ? (s_raw + (long)nd * G + g) : (denom + nd);
          if (enc & 1) *pd = v; else atomicAdd(pd, v);
        }
      }
    }
  }
}

// ---------------- fused ctx + GRU kernel v4 (KEPT): 16 rows/block, 2 waves splitting column tiles ----------------
// Confirmed win in round 10: rest-of-pipeline 303 -> 283us (grid 782->1563, ~12 waves/CU).
#define XST 420
__global__ __launch_bounds__(128, 2) void ctxgru_kernel(
    const float* __restrict__ s_raw, const u16* __restrict__ hvb, const float* __restrict__ denom,
    const u16* __restrict__ Wet2, const u16* __restrict__ Wrz,
    const u16* __restrict__ Winn, const u16* __restrict__ Whn,
    const float* __restrict__ bet, const float* __restrict__ b_ih, const float* __restrict__ b_hh,
    float* __restrict__ out, int M)
{
  __shared__ __align__(16) u16 X[16 * XST];
  __shared__ float invds[16];
  int tid = threadIdx.x;
  int m0 = blockIdx.x * 16;

  if (tid < 16){
    float dn = (m0 + tid < M) ? denom[m0 + tid] : 0.f;
    invds[tid] = dn > 0.f ? 1.f / dn : 0.f;
  }
  __syncthreads();

  for (int idx = tid; idx < 16 * 50; idx += 128){
    int r = idx / 50, c = idx % 50;
    int row = m0 + r;
    float4 v = make_float4(0.f,0.f,0.f,0.f);
    ushort4 h = make_ushort4(0,0,0,0);
    if (row < M){
      v = *(const float4*)(s_raw + (long)row * G + c * 4);
      h = *(const ushort4*)(hvb + (long)row * G + c * 4);
    }
    float iv = invds[r];
    *(ushort4*)&X[r * XST + c * 4] = make_ushort4(f2b(v.x*iv), f2b(v.y*iv), f2b(v.z*iv), f2b(v.w*iv));
    *(ushort4*)&X[r * XST + 208 + c * 4] = h;
  }
  for (int idx = tid; idx < 16 * 4; idx += 128){
    int r = idx / 4, q = idx % 4;
    int base = (q < 2) ? (200 + q * 4) : (408 + (q - 2) * 4);
    *(ushort4*)&X[r * XST + base] = make_ushort4(0,0,0,0);
  }
  __syncthreads();

  int l = tid & 63, w = tid >> 6, quad = l >> 4, col = l & 15;
  int st0 = (w == 0) ? 0 : 7;
  int stn = (w == 0) ? 7 : 6;

  // ---- phase 1: ctx (wave w computes its 7/6 column tiles for all 16 rows) ----
  bfrag a1[7];
  #pragma unroll
  for (int j = 0; j < 7; ++j) a1[j] = *(const bfrag*)&X[col * XST + j * 32 + quad * 8];

  for (int ii = 0; ii < stn; ++ii){
    int st = st0 + ii;
    int n = st * 16 + col;
    ffrag acc; acc.x = 0.f; acc.y = 0.f; acc.z = 0.f; acc.w = 0.f;
    #pragma unroll
    for (int j = 0; j < 7; ++j){
      bfrag b = *(const bfrag*)(Wet2 + (long)n * 224 + j * 32 + quad * 8);
      acc = MFMA16(a1[j], b, acc);
    }
    if (n < G){
      float bv = bet[n];
      #pragma unroll
      for (int r = 0; r < 4; ++r){
        int lr = quad * 4 + r;
        float gate = invds[lr] > 0.f ? 1.f : 0.f;
        float v = acc[r] + gate * bv;
        v = (v > 0.f) ? v : (__expf(v) - 1.f);
        X[lr * XST + n] = f2b(v);
      }
    }
  }
  __syncthreads();

  // ---- phase 2: gates + GRU (same 7/6 split) ----
  bfrag a2[13];
  #pragma unroll
  for (int j = 0; j < 13; ++j) a2[j] = *(const bfrag*)&X[col * XST + j * 32 + quad * 8];

  for (int ii = 0; ii < stn; ++ii){
    int st = st0 + ii;
    int n = st * 16 + col;
    ffrag ar, az, ai, ah;
    ar.x=ar.y=ar.z=ar.w=0.f; az.x=az.y=az.z=az.w=0.f;
    ai.x=ai.y=ai.z=ai.w=0.f; ah.x=ah.y=ah.z=ah.w=0.f;
    #pragma unroll
    for (int j = 0; j < 13; ++j){
      bfrag br_ = *(const bfrag*)(Wrz + (long)n * 416 + j * 32 + quad * 8);
      ar = MFMA16(a2[j], br_, ar);
      bfrag bz_ = *(const bfrag*)(Wrz + (long)(208 + n) * 416 + j * 32 + quad * 8);
      az = MFMA16(a2[j], bz_, az);
    }
    #pragma unroll
    for (int j = 0; j < 7; ++j){
      bfrag bi_ = *(const bfrag*)(Winn + (long)n * 224 + j * 32 + quad * 8);
      ai = MFMA16(a2[j], bi_, ai);
      bfrag bh_ = *(const bfrag*)(Whn + (long)n * 224 + j * 32 + quad * 8);
      ah = MFMA16(a2[j + 6], bh_, ah);
    }
    if (n < G){
      float br = b_ih[n] + b_hh[n];
      float bz = b_ih[G + n] + b_hh[G + n];
      float bi = b_ih[2 * G + n];
      float bh = b_hh[2 * G + n];
      #pragma unroll
      for (int r = 0; r < 4; ++r){
        int lr = quad * 4 + r;
        int row = m0 + lr;
        if (row < M){
          float rg = 1.f / (1.f + __expf(-(ar[r] + br)));
          float zg = 1.f / (1.f + __expf(-(az[r] + bz)));
          float ng = tanhf(ai[r] + bi + rg * (ah[r] + bh));
          float hvv = b2f(X[lr * XST + 208 + n]);
          float h = (1.f - zg) * ng + zg * hvv;
          out[(long)row * G + n] = h > 0.f ? h : 0.f;
        }
      }
    }
  }
}

extern "C" void kernel_launch(void* const* d_in, const int* in_sizes, int n_in,
                              void* d_out, int out_size, void* d_ws, size_t ws_size,
                              hipStream_t stream)
{
  const float* nf   = (const float*)d_in[0];
  const float* ef   = (const float*)d_in[1];
  const int*   src  = (const int*)d_in[2];
  const int*   dst  = (const int*)d_in[3];
  const float* Wn   = (const float*)d_in[4];
  const float* bn   = (const float*)d_in[5];
  const float* We1  = (const float*)d_in[6];
  const float* be1  = (const float*)d_in[7];
  const float* We2  = (const float*)d_in[8];
  const float* be2  = (const float*)d_in[9];
  const float* Wet  = (const float*)d_in[10];
  const float* bet  = (const float*)d_in[11];
  const float* W_ih = (const float*)d_in[12];
  const float* b_ih = (const float*)d_in[13];
  const float* W_hh = (const float*)d_in[14];
  const float* b_hh = (const float*)d_in[15];
  int N = in_sizes[0] / NDIM;   // 25000
  int E = in_sizes[2];          // 500000
  float* out = (float*)d_out;

  char* p = (char*)d_ws;
  auto alloc = [&](size_t b){ char* r = p; p += (b + 255) & ~(size_t)255; return r; };
  u16*   hvb   = (u16*)  alloc((size_t)N * G * 2);
  float* s_raw = (float*)alloc((size_t)N * G * 4);
  float* denom = (float*)alloc((size_t)N * 4);
  int*   deg   = (int*)  alloc((size_t)N * 4);
  int*   offs  = (int*)  alloc((size_t)(N + 1) * 4);
  int*   cur   = (int*)  alloc((size_t)N * 4);
  u32*   erec  = (u32*)  alloc((size_t)E * 64);
  u16*   nfb   = (u16*)  alloc((size_t)N * NDIM * 2);
  float* l1    = (float*)alloc((size_t)N * 4);
  u16*   Wbg   = (u16*)  alloc((size_t)208 * 64 * 2);
  u16*   Wnb   = (u16*)  alloc((size_t)256 * 64 * 2);
  u16*   Wet2  = (u16*)  alloc((size_t)208 * 224 * 2);
  u16*   Wrz   = (u16*)  alloc((size_t)2 * 208 * 416 * 2);
  u16*   Winn  = (u16*)  alloc((size_t)208 * 224 * 2);
  u16*   Whn   = (u16*)  alloc((size_t)208 * 224 * 2);
  u32*   bwt   = (u32*)  alloc((size_t)208 * 4);

  int eb = (E + 255) / 256;
  int mb = (N + 63) / 64;
  int mb3 = (N + 15) / 16;

  init_kernel<<<dim3((N * G + 255) / 256), dim3(256), 0, stream>>>(
      s_raw, denom, deg, l1, nf, nfb, We1, Wn, Wet, W_ih, W_hh, be1, We2,
      Wbg, Wnb, Wet2, Wrz, Winn, Whn, bwt, N);
  deghist_kernel<<<dim3(eb), dim3(256), 0, stream>>>(dst, deg, E);
  scan_kernel<<<dim3(1), dim3(1024), 0, stream>>>(deg, offs, cur, N);
  hvgemm_kernel<<<dim3(4, mb), dim3(256), 0, stream>>>(nf, Wnb, bn, We2, hvb, l1, N);
  scatter_pack_kernel<<<dim3(eb), dim3(256), 0, stream>>>(dst, src, ef, l1, cur, erec, E);
  edge_csr_kernel<<<dim3((E + 63) / 64), dim3(128), 0, stream>>>(nfb, erec, offs,
                                                                 Wbg, bwt, be2, s_raw, denom, E);
  ctxgru_kernel<<<dim3(mb3), dim3(128), 0, stream>>>(s_raw, hvb, denom, Wet2, Wrz, Winn, Whn,
                                                     bet, b_ih, b_hh, out, N);
}

// Round 12
// 396.595 us; speedup vs baseline: 1.0405x; 1.0107x over previous
//
#include <hip/hip_runtime.h>
#include <hip/hip_bf16.h>

#define G 200
#define NDIM 32
#define EDIM 19
#define KIN 51  // NDIM + EDIM

typedef unsigned short u16;
typedef unsigned int u32;
typedef unsigned long long u64;

typedef __attribute__((ext_vector_type(8))) short bfrag;   // 8 bf16 (4 VGPRs)
typedef __attribute__((ext_vector_type(4))) float ffrag;   // 4 fp32 acc

__device__ __forceinline__ float lrelu(float x){ return x > 0.f ? x : 0.01f*x; }
__device__ __forceinline__ u16 f2b(float x){ u32 u = __float_as_uint(x); return (u16)((u + 0x7fffu + ((u >> 16) & 1u)) >> 16); }
__device__ __forceinline__ float b2f(u16 x){ return __uint_as_float(((u32)x) << 16); }
// HW packed f32->bf16 RNE pair -- used ONLY inside edge_csr's MFMA-interleaved staging
__device__ __forceinline__ u32 f2b2(float a, float b){
  u32 r;
  asm("v_cvt_pk_bf16_f32 %0, %1, %2" : "=v"(r) : "v"(a), "v"(b));
  return r;
}

#define MFMA16(a, b, c) __builtin_amdgcn_mfma_f32_16x16x32_bf16(a, b, c, 0, 0, 0)

// ---------------- init v2: nf->bf16 + degree hist + weight prep + bwt (zeroing -> hipMemsetAsync) ----------------
// Grid shrunk 19532 -> 3125 blocks (covers N*NDIM=800K > E=500K > prep_total=342K).
__global__ void init_kernel(const int* __restrict__ dst, int* __restrict__ deg,
                            const float* __restrict__ nf, u16* __restrict__ nfb,
                            const float* __restrict__ We1, const float* __restrict__ Wn,
                            const float* __restrict__ Wet, const float* __restrict__ Wih,
                            const float* __restrict__ Whh,
                            const float* __restrict__ be1, const float* __restrict__ We2,
                            u16* __restrict__ Wbg, u16* __restrict__ Wnb, u16* __restrict__ Wet2,
                            u16* __restrict__ Wrz, u16* __restrict__ Winn, u16* __restrict__ Whn,
                            u32* __restrict__ bwt, int N, int E){
  int i = blockIdx.x * 256 + threadIdx.x;
  if (i < N * NDIM) nfb[i] = f2b(nf[i]);
  if (i < E) atomicAdd(&deg[dst[i]], 1);
  if (i < 208){
    float bv = (i < G) ? be1[i] : 0.f;
    float wv = (i < G) ? We2[G + i] : 0.f;
    bwt[i] = (u32)f2b(bv) | ((u32)f2b(wv) << 16);
  }

  int idx = i;
  const int s0 = 208 * 64, s1 = 256 * 64, s2 = 208 * 224, s3 = 2 * 208 * 416, s4 = 208 * 224, s5 = 208 * 224;
  if (idx < s0){
    int r = idx >> 6, k = idx & 63;
    Wbg[idx] = f2b((r < G && k < KIN) ? We1[r * KIN + k] : 0.f);
    return;
  }
  idx -= s0;
  if (idx < s1){
    int r = idx >> 6, k = idx & 63;
    Wnb[idx] = f2b((r < G && k < NDIM) ? Wn[r * NDIM + k] : 0.f);
    return;
  }
  idx -= s1;
  if (idx < s2){
    int r = idx / 224, k = idx % 224;
    Wet2[idx] = f2b((r < G && k < G) ? Wet[r * G + k] : 0.f);
    return;
  }
  idx -= s2;
  if (idx < s3){
    int g = idx / (208 * 416), rem = idx % (208 * 416);
    int r = rem / 416, k = rem % 416;
    float v = 0.f;
    if (r < G){
      int row = g * G + r;
      if (k < G) v = Wih[row * G + k];
      else if (k >= 208 && k < 408) v = Whh[row * G + (k - 208)];
    }
    Wrz[idx] = f2b(v);
    return;
  }
  idx -= s3;
  if (idx < s4){
    int r = idx / 224, k = idx % 224;
    Winn[idx] = f2b((r < G && k < G) ? Wih[(2 * G + r) * G + k] : 0.f);
    return;
  }
  idx -= s4;
  if (idx < s5){
    int r = idx / 224, kk = idx % 224;
    Whn[idx] = f2b((r < G && kk >= 16 && kk < 216) ? Whh[(2 * G + r) * G + (kk - 16)] : 0.f);
  }
}

// ---------------- single-pass block scan, LDS-staged coalesced loads ----------------
__global__ __launch_bounds__(1024) void scan_kernel(const int* __restrict__ deg, int* __restrict__ offs,
                                                    int* __restrict__ cur, int N){
  __shared__ int sd[12800];
  __shared__ int wsums[16];
  const int C = 25;  // 1024*25 = 25600 >= N
  int tid = threadIdx.x;
  int lane = tid & 63, wid = tid >> 6;
  int val[C];
  for (int h = 0; h < 2; ++h){
    int base_h = h * 12800;
    for (int k = tid; k < 12800; k += 1024){
      int gi = base_h + k;
      sd[k] = (gi < N) ? deg[gi] : 0;
    }
    __syncthreads();
    if ((tid >> 9) == h){
      int t0 = (tid - h * 512) * C;
      #pragma unroll
      for (int i = 0; i < C; ++i) val[i] = sd[t0 + i];
    }
    __syncthreads();
  }
  int s = 0;
  #pragma unroll
  for (int i = 0; i < C; ++i){ int v = val[i]; val[i] = s; s += v; }
  int x = s;
  #pragma unroll
  for (int off = 1; off < 64; off <<= 1){
    int y = __shfl_up(x, off, 64);
    if (lane >= off) x += y;
  }
  if (lane == 63) wsums[wid] = x;
  __syncthreads();
  if (wid == 0){
    int w = (lane < 16) ? wsums[lane] : 0;
    #pragma unroll
    for (int off = 1; off < 16; off <<= 1){
      int y = __shfl_up(w, off, 64);
      if (lane >= off) w += y;
    }
    if (lane < 16) wsums[lane] = w;
  }
  __syncthreads();
  int excl = ((wid ? wsums[wid - 1] : 0) + x) - s;
  int base = tid * C;
  #pragma unroll
  for (int i = 0; i < C; ++i){
    int o = excl + val[i];
    if (base + i < N){ offs[base + i] = o; cur[base + i] = o; }
  }
  if (tid == 1023) offs[N] = excl + s;
}

// ---------------- scatter + pack: ONE aligned 64B record per edge ----------------
// record (u32[16]): [0]=dst [1]=src [2]=l1[dst] bits [3]=0 [4..15]=24 bf16 edge feats
__global__ void scatter_pack_kernel(const int* __restrict__ dst, const int* __restrict__ src,
                                    const float* __restrict__ ef, const float* __restrict__ l1,
                                    int* __restrict__ cur, u32* __restrict__ erec, int E){
  int e = blockIdx.x * 256 + threadIdx.x;
  if (e >= E) return;
  int d = dst[e];
  int pos = atomicAdd(&cur[d], 1);
  u32 w[16];
  w[0] = (u32)d; w[1] = (u32)src[e]; w[2] = __float_as_uint(l1[d]); w[3] = 0u;
  const float* ep = ef + (long)e * EDIM;
  #pragma unroll
  for (int j = 0; j < 9; ++j) w[4 + j] = (u32)f2b(ep[2 * j]) | ((u32)f2b(ep[2 * j + 1]) << 16);
  w[13] = (u32)f2b(ep[18]);
  w[14] = 0u; w[15] = 0u;
  uint4* dp = (uint4*)(erec + (size_t)pos * 16);
  dp[0] = make_uint4(w[0], w[1], w[2], w[3]);
  dp[1] = make_uint4(w[4], w[5], w[6], w[7]);
  dp[2] = make_uint4(w[8], w[9], w[10], w[11]);
  dp[3] = make_uint4(w[12], w[13], w[14], w[15]);
}

// ---------------- hv GEMM + fused l1 partials: hvb = bf16(lrelu(nf@Wn^T+bn)); l1 += We2[.]·hv ----------------
__global__ __launch_bounds__(256) void hvgemm_kernel(
    const float* __restrict__ nf, const u16* __restrict__ Wnb, const float* __restrict__ bn,
    const float* __restrict__ We2, u16* __restrict__ hvb, float* __restrict__ l1, int M)
{
  __shared__ __align__(16) u16 As[64][72];
  __shared__ __align__(16) u16 Ws[64][72];
  int tid = threadIdx.x;
  int m0 = blockIdx.y * 64, n0 = blockIdx.x * 64;
  int l = tid & 63, w = tid >> 6, quad = l >> 4, col = l & 15;

  for (int idx = tid; idx < 64 * 16; idx += 256){
    int r = idx >> 4, c4 = idx & 15;
    int row = m0 + r, k = c4 * 4;
    float4 v = make_float4(0.f,0.f,0.f,0.f);
    if (row < M && k < NDIM) v = *(const float4*)(nf + (long)row * NDIM + k);
    *(ushort4*)&As[r][c4 * 4] = make_ushort4(f2b(v.x), f2b(v.y), f2b(v.z), f2b(v.w));
  }
  for (int idx = tid; idx < 64 * 8; idx += 256){
    int r = idx >> 3, c = idx & 7;
    *(ulonglong2*)&Ws[r][c * 8] = *(const ulonglong2*)(Wnb + (long)(n0 + r) * 64 + c * 8);
  }
  __syncthreads();
  bfrag a0 = *(const bfrag*)&As[w * 16 + col][quad * 8];
  bfrag a1 = *(const bfrag*)&As[w * 16 + col][32 + quad * 8];
  ffrag acc[4];
  #pragma unroll
  for (int t = 0; t < 4; ++t){ acc[t].x = 0.f; acc[t].y = 0.f; acc[t].z = 0.f; acc[t].w = 0.f; }
  #pragma unroll
  for (int t = 0; t < 4; ++t){
    bfrag b0 = *(const bfrag*)&Ws[t * 16 + col][quad * 8];
    bfrag b1 = *(const bfrag*)&Ws[t * 16 + col][32 + quad * 8];
    acc[t] = MFMA16(a0, b0, acc[t]);
    acc[t] = MFMA16(a1, b1, acc[t]);
  }
  float lp[4] = {0.f, 0.f, 0.f, 0.f};
  #pragma unroll
  for (int t = 0; t < 4; ++t){
    int n = n0 + t * 16 + col;
    float bv = (n < G) ? bn[n] : 0.f;
    float wv = (n < G) ? We2[n] : 0.f;
    #pragma unroll
    for (int r = 0; r < 4; ++r){
      int row = m0 + w * 16 + quad * 4 + r;
      float v = lrelu(acc[t][r] + bv);
      lp[r] += wv * v;
      if (n < G && row < M) hvb[(long)row * G + n] = f2b(v);
    }
  }
  #pragma unroll
  for (int r = 0; r < 4; ++r){
    lp[r] += __shfl_xor(lp[r], 1, 16);
    lp[r] += __shfl_xor(lp[r], 2, 16);
    lp[r] += __shfl_xor(lp[r], 4, 16);
    lp[r] += __shfl_xor(lp[r], 8, 16);
  }
  if (col == 0){
    #pragma unroll
    for (int r = 0; r < 4; ++r){
      int row = m0 + w * 16 + quad * 4 + r;
      if (row < M) atomicAdd(&l1[row], lp[r]);
    }
  }
}

// ---------------- CSR edge kernel v10 (FROZEN): best-measured state, 5 consistent runs at ~107us ----------------
#define SST 72
__global__ __launch_bounds__(128, 2) void edge_csr_kernel(
    const u16* __restrict__ nfb, const u32* __restrict__ erec, const int* __restrict__ offs,
    const u16* __restrict__ Wbg, const u32* __restrict__ bwt, const float* __restrict__ be2,
    float* __restrict__ s_raw, float* __restrict__ denom, int E)
{
  __shared__ __align__(16) u16 shm[208 * SST];  // stageT [208][72]
  __shared__ int segnode[64];
  __shared__ __align__(16) u16 exb[64];
  __shared__ __align__(8) unsigned char segb[64];
  __shared__ int Svar;

  int tid = threadIdx.x;
  int j0 = blockIdx.x * 64;
  int l = tid & 63, w = tid >> 6;        // w in {0,1}
  int quad = l >> 4, col = l & 15;
  int m0a = w * 32, m0b = w * 32 + 16;

  // ---- issue longest-latency chains first: src index -> nfb gather (HBM-random) ----
  int ja = j0 + m0a + col;
  int jb = j0 + m0b + col;
  bool va = ja < E, vb = jb < E;
  int sa = va ? (int)erec[(size_t)ja * 16 + 1] : 0;
  int sb = vb ? (int)erec[(size_t)jb * 16 + 1] : 0;
  bfrag a0a = {0,0,0,0,0,0,0,0}, a1a = {0,0,0,0,0,0,0,0};
  bfrag a0b = {0,0,0,0,0,0,0,0}, a1b = {0,0,0,0,0,0,0,0};
  if (va){
    a0a = *(const bfrag*)(nfb + (long)sa * NDIM + quad * 8);
    if (quad < 3) a1a = *(const bfrag*)((const u16*)erec + (size_t)ja * 32 + 8 + quad * 8);
  }
  if (vb){
    a0b = *(const bfrag*)(nfb + (long)sb * NDIM + quad * 8);
    if (quad < 3) a1b = *(const bfrag*)((const u16*)erec + (size_t)jb * 32 + 8 + quad * 8);
  }

  // ---- prefetch ALL B fragments + bias/weight words into registers (L2-hot burst) ----
  bfrag B0[13], B1[13];
  u32 bwp[13];
  #pragma unroll
  for (int t = 0; t < 13; ++t){
    B0[t] = *(const bfrag*)(Wbg + (t * 16 + col) * 64 + quad * 8);
    B1[t] = *(const bfrag*)(Wbg + (t * 16 + col) * 64 + 32 + quad * 8);
    bwp[t] = bwt[t * 16 + col];
  }

  // ---- meta: wave 0 only (overlaps the loads above) ----
  if (tid < 64){
    int j = j0 + tid;
    int valid = j < E;
    int n = valid ? (int)erec[(size_t)j * 16] : -1;
    int nn = (tid == 63 || j + 1 >= E) ? -2 : (int)erec[(size_t)(j + 1) * 16];
    int f1 = (valid && n != nn) ? 1 : 0;
    int f2 = 0;
    if (f1 && offs[n] >= j0 && offs[n + 1] <= j0 + 64) f2 = 1;
    u64 em = __ballot(f1 != 0);
    int seg = (int)__popcll(em & ((1ull << tid) - 1ull));
    segb[tid] = (unsigned char)seg;
    if (f1) segnode[seg] = (n << 1) | f2;
    if (tid == 0) Svar = (int)__popcll(em);
    shm[200 * SST + tid] = 0x3F80;  // ones row (for denom)
  }

  // ---- phase 1: 13 he1 tiles x 2 strips, pure-register operands ----
  float pla[4] = {0.f, 0.f, 0.f, 0.f};
  float plb[4] = {0.f, 0.f, 0.f, 0.f};
  #pragma unroll
  for (int t = 0; t < 13; ++t){
    ffrag acca; acca.x = 0.f; acca.y = 0.f; acca.z = 0.f; acca.w = 0.f;
    ffrag accb; accb.x = 0.f; accb.y = 0.f; accb.z = 0.f; accb.w = 0.f;
    acca = MFMA16(a0a, B0[t], acca);
    acca = MFMA16(a1a, B1[t], acca);
    accb = MFMA16(a0b, B0[t], accb);
    accb = MFMA16(a1b, B1[t], accb);
    int g = t * 16 + col;
    u32 bw = bwp[t];
    float bv = b2f((u16)(bw & 0xFFFF)), wv = b2f((u16)(bw >> 16));
    float u0 = lrelu(acca.x + bv), u1 = lrelu(acca.y + bv);
    float u2 = lrelu(acca.z + bv), u3 = lrelu(acca.w + bv);
    pla[0] += wv * u0; pla[1] += wv * u1; pla[2] += wv * u2; pla[3] += wv * u3;
    float v0 = lrelu(accb.x + bv), v1 = lrelu(accb.y + bv);
    float v2 = lrelu(accb.z + bv), v3 = lrelu(accb.w + bv);
    plb[0] += wv * v0; plb[1] += wv * v1; plb[2] += wv * v2; plb[3] += wv * v3;
    if (g < G){
      *(uint2*)&shm[g * SST + m0a + quad * 4] = make_uint2(f2b2(u0, u1), f2b2(u2, u3));
      *(uint2*)&shm[g * SST + m0b + quad * 4] = make_uint2(f2b2(v0, v1), f2b2(v2, v3));
    }
  }
  #pragma unroll
  for (int r = 0; r < 4; ++r){
    pla[r] += __shfl_xor(pla[r], 1, 16);
    pla[r] += __shfl_xor(pla[r], 2, 16);
    pla[r] += __shfl_xor(pla[r], 4, 16);
    pla[r] += __shfl_xor(pla[r], 8, 16);
    plb[r] += __shfl_xor(plb[r], 1, 16);
    plb[r] += __shfl_xor(plb[r], 2, 16);
    plb[r] += __shfl_xor(plb[r], 4, 16);
    plb[r] += __shfl_xor(plb[r], 8, 16);
  }
  if (col == 0){
    #pragma unroll
    for (int r = 0; r < 4; ++r){
      int ea = m0a + quad * 4 + r;
      float exa = 0.f;
      if (j0 + ea < E){
        float l1v = __uint_as_float(erec[(size_t)(j0 + ea) * 16 + 2]);
        exa = __expf(lrelu(pla[r] + l1v + be2[0]));
      }
      exb[ea] = f2b(exa);
      int eb = m0b + quad * 4 + r;
      float exv = 0.f;
      if (j0 + eb < E){
        float l1v = __uint_as_float(erec[(size_t)(j0 + eb) * 16 + 2]);
        exv = __expf(lrelu(plb[r] + l1v + be2[0]));
      }
      exb[eb] = f2b(exv);
    }
  }
  __syncthreads();  // the ONLY barrier

  // ---- phase 2: MFMA segment reduction (tiles 0..6 -> wave 0, 7..12 -> wave 1) ----
  int S = Svar;
  for (int mt = 0; mt * 16 < S; ++mt){
    int m = mt * 16 + col;
    u64 sb0 = *(const u64*)&segb[quad * 8];
    u64 sb1 = *(const u64*)&segb[32 + quad * 8];
    ulonglong2 ew0 = *(const ulonglong2*)&exb[quad * 8];
    ulonglong2 ew1 = *(const ulonglong2*)&exb[32 + quad * 8];
    bfrag A0, A1;
    #pragma unroll
    for (int jj = 0; jj < 8; ++jj){
      int s0i = (int)((sb0 >> (8 * jj)) & 0xFF);
      int s1i = (int)((sb1 >> (8 * jj)) & 0xFF);
      u64 w0 = (jj < 4) ? ew0.x : ew0.y;
      u64 w1 = (jj < 4) ? ew1.x : ew1.y;
      u16 e0 = (u16)(w0 >> (16 * (jj & 3)));
      u16 e1 = (u16)(w1 >> (16 * (jj & 3)));
      A0[jj] = (s0i == m) ? (short)e0 : (short)0;
      A1[jj] = (s1i == m) ? (short)e1 : (short)0;
    }
    int t0 = (w == 0) ? 0 : 7;
    int cnt = (w == 0) ? 7 : 6;
    for (int i = 0; i < cnt; ++i){
      int t = t0 + i;
      bfrag b0 = *(const bfrag*)&shm[(t * 16 + col) * SST + quad * 8];
      bfrag b1 = *(const bfrag*)&shm[(t * 16 + col) * SST + 32 + quad * 8];
      ffrag acc; acc.x = 0.f; acc.y = 0.f; acc.z = 0.f; acc.w = 0.f;
      acc = MFMA16(A0, b0, acc);
      acc = MFMA16(A1, b1, acc);
      int g = t * 16 + col;
      #pragma unroll
      for (int r = 0; r < 4; ++r){
        int seg = mt * 16 + quad * 4 + r;
        if (seg < S && g <= 200){
          int enc = segnode[seg];
          int nd = enc >> 1;
          float v = acc[r];
          float* pd = (g < G) ? (s_raw + (long)nd * G + g) : (denom + nd);
          if (enc & 1) *pd = v; else atomicAdd(pd, v);
        }
      }
    }
  }
}

// ---------------- fused ctx + GRU kernel v4 (KEPT): 16 rows/block, 2 waves splitting column tiles ----------------
#define XST 420
__global__ __launch_bounds__(128, 2) void ctxgru_kernel(
    const float* __restrict__ s_raw, const u16* __restrict__ hvb, const float* __restrict__ denom,
    const u16* __restrict__ Wet2, const u16* __restrict__ Wrz,
    const u16* __restrict__ Winn, const u16* __restrict__ Whn,
    const float* __restrict__ bet, const float* __restrict__ b_ih, const float* __restrict__ b_hh,
    float* __restrict__ out, int M)
{
  __shared__ __align__(16) u16 X[16 * XST];
  __shared__ float invds[16];
  int tid = threadIdx.x;
  int m0 = blockIdx.x * 16;

  if (tid < 16){
    float dn = (m0 + tid < M) ? denom[m0 + tid] : 0.f;
    invds[tid] = dn > 0.f ? 1.f / dn : 0.f;
  }
  __syncthreads();

  for (int idx = tid; idx < 16 * 50; idx += 128){
    int r = idx / 50, c = idx % 50;
    int row = m0 + r;
    float4 v = make_float4(0.f,0.f,0.f,0.f);
    ushort4 h = make_ushort4(0,0,0,0);
    if (row < M){
      v = *(const float4*)(s_raw + (long)row * G + c * 4);
      h = *(const ushort4*)(hvb + (long)row * G + c * 4);
    }
    float iv = invds[r];
    *(ushort4*)&X[r * XST + c * 4] = make_ushort4(f2b(v.x*iv), f2b(v.y*iv), f2b(v.z*iv), f2b(v.w*iv));
    *(ushort4*)&X[r * XST + 208 + c * 4] = h;
  }
  for (int idx = tid; idx < 16 * 4; idx += 128){
    int r = idx / 4, q = idx % 4;
    int base = (q < 2) ? (200 + q * 4) : (408 + (q - 2) * 4);
    *(ushort4*)&X[r * XST + base] = make_ushort4(0,0,0,0);
  }
  __syncthreads();

  int l = tid & 63, w = tid >> 6, quad = l >> 4, col = l & 15;
  int st0 = (w == 0) ? 0 : 7;
  int stn = (w == 0) ? 7 : 6;

  // ---- phase 1: ctx (wave w computes its 7/6 column tiles for all 16 rows) ----
  bfrag a1[7];
  #pragma unroll
  for (int j = 0; j < 7; ++j) a1[j] = *(const bfrag*)&X[col * XST + j * 32 + quad * 8];

  for (int ii = 0; ii < stn; ++ii){
    int st = st0 + ii;
    int n = st * 16 + col;
    ffrag acc; acc.x = 0.f; acc.y = 0.f; acc.z = 0.f; acc.w = 0.f;
    #pragma unroll
    for (int j = 0; j < 7; ++j){
      bfrag b = *(const bfrag*)(Wet2 + (long)n * 224 + j * 32 + quad * 8);
      acc = MFMA16(a1[j], b, acc);
    }
    if (n < G){
      float bv = bet[n];
      #pragma unroll
      for (int r = 0; r < 4; ++r){
        int lr = quad * 4 + r;
        float gate = invds[lr] > 0.f ? 1.f : 0.f;
        float v = acc[r] + gate * bv;
        v = (v > 0.f) ? v : (__expf(v) - 1.f);
        X[lr * XST + n] = f2b(v);
      }
    }
  }
  __syncthreads();

  // ---- phase 2: gates + GRU (same 7/6 split) ----
  bfrag a2[13];
  #pragma unroll
  for (int j = 0; j < 13; ++j) a2[j] = *(const bfrag*)&X[col * XST + j * 32 + quad * 8];

  for (int ii = 0; ii < stn; ++ii){
    int st = st0 + ii;
    int n = st * 16 + col;
    ffrag ar, az, ai, ah;
    ar.x=ar.y=ar.z=ar.w=0.f; az.x=az.y=az.z=az.w=0.f;
    ai.x=ai.y=ai.z=ai.w=0.f; ah.x=ah.y=ah.z=ah.w=0.f;
    #pragma unroll
    for (int j = 0; j < 13; ++j){
      bfrag br_ = *(const bfrag*)(Wrz + (long)n * 416 + j * 32 + quad * 8);
      ar = MFMA16(a2[j], br_, ar);
      bfrag bz_ = *(const bfrag*)(Wrz + (long)(208 + n) * 416 + j * 32 + quad * 8);
      az = MFMA16(a2[j], bz_, az);
    }
    #pragma unroll
    for (int j = 0; j < 7; ++j){
      bfrag bi_ = *(const bfrag*)(Winn + (long)n * 224 + j * 32 + quad * 8);
      ai = MFMA16(a2[j], bi_, ai);
      bfrag bh_ = *(const bfrag*)(Whn + (long)n * 224 + j * 32 + quad * 8);
      ah = MFMA16(a2[j + 6], bh_, ah);
    }
    if (n < G){
      float br = b_ih[n] + b_hh[n];
      float bz = b_ih[G + n] + b_hh[G + n];
      float bi = b_ih[2 * G + n];
      float bh = b_hh[2 * G + n];
      #pragma unroll
      for (int r = 0; r < 4; ++r){
        int lr = quad * 4 + r;
        int row = m0 + lr;
        if (row < M){
          float rg = 1.f / (1.f + __expf(-(ar[r] + br)));
          float zg = 1.f / (1.f + __expf(-(az[r] + bz)));
          float ng = tanhf(ai[r] + bi + rg * (ah[r] + bh));
          float hvv = b2f(X[lr * XST + 208 + n]);
          float h = (1.f - zg) * ng + zg * hvv;
          out[(long)row * G + n] = h > 0.f ? h : 0.f;
        }
      }
    }
  }
}

extern "C" void kernel_launch(void* const* d_in, const int* in_sizes, int n_in,
                              void* d_out, int out_size, void* d_ws, size_t ws_size,
                              hipStream_t stream)
{
  const float* nf   = (const float*)d_in[0];
  const float* ef   = (const float*)d_in[1];
  const int*   src  = (const int*)d_in[2];
  const int*   dst  = (const int*)d_in[3];
  const float* Wn   = (const float*)d_in[4];
  const float* bn   = (const float*)d_in[5];
  const float* We1  = (const float*)d_in[6];
  const float* be1  = (const float*)d_in[7];
  const float* We2  = (const float*)d_in[8];
  const float* be2  = (const float*)d_in[9];
  const float* Wet  = (const float*)d_in[10];
  const float* bet  = (const float*)d_in[11];
  const float* W_ih = (const float*)d_in[12];
  const float* b_ih = (const float*)d_in[13];
  const float* W_hh = (const float*)d_in[14];
  const float* b_hh = (const float*)d_in[15];
  int N = in_sizes[0] / NDIM;   // 25000
  int E = in_sizes[2];          // 500000
  float* out = (float*)d_out;

  char* p = (char*)d_ws;
  auto alloc = [&](size_t b){ char* r = p; p += (b + 255) & ~(size_t)255; return r; };
  u16*   hvb   = (u16*)  alloc((size_t)N * G * 2);
  float* s_raw = (float*)alloc((size_t)N * G * 4);
  int*   zb    = (int*)  alloc((size_t)3 * N * 4);   // [denom | deg | l1] contiguous, one memset
  float* denom = (float*)zb;
  int*   deg   = zb + N;
  float* l1    = (float*)(zb + 2 * N);
  int*   offs  = (int*)  alloc((size_t)(N + 1) * 4);
  int*   cur   = (int*)  alloc((size_t)N * 4);
  u32*   erec  = (u32*)  alloc((size_t)E * 64);
  u16*   nfb   = (u16*)  alloc((size_t)N * NDIM * 2);
  u16*   Wbg   = (u16*)  alloc((size_t)208 * 64 * 2);
  u16*   Wnb   = (u16*)  alloc((size_t)256 * 64 * 2);
  u16*   Wet2  = (u16*)  alloc((size_t)208 * 224 * 2);
  u16*   Wrz   = (u16*)  alloc((size_t)2 * 208 * 416 * 2);
  u16*   Winn  = (u16*)  alloc((size_t)208 * 224 * 2);
  u16*   Whn   = (u16*)  alloc((size_t)208 * 224 * 2);
  u32*   bwt   = (u32*)  alloc((size_t)208 * 4);

  int eb = (E + 255) / 256;
  int mb = (N + 63) / 64;
  int mb3 = (N + 15) / 16;
  int ib = (N * NDIM + 255) / 256;   // 3125 blocks: covers N*NDIM=800K > E=500K > prep_total=342K

  hipMemsetAsync(s_raw, 0, (size_t)N * G * 4, stream);
  hipMemsetAsync(zb, 0, (size_t)3 * N * 4, stream);
  init_kernel<<<dim3(ib), dim3(256), 0, stream>>>(
      dst, deg, nf, nfb, We1, Wn, Wet, W_ih, W_hh, be1, We2,
      Wbg, Wnb, Wet2, Wrz, Winn, Whn, bwt, N, E);
  scan_kernel<<<dim3(1), dim3(1024), 0, stream>>>(deg, offs, cur, N);
  hvgemm_kernel<<<dim3(4, mb), dim3(256), 0, stream>>>(nf, Wnb, bn, We2, hvb, l1, N);
  scatter_pack_kernel<<<dim3(eb), dim3(256), 0, stream>>>(dst, src, ef, l1, cur, erec, E);
  edge_csr_kernel<<<dim3((E + 63) / 64), dim3(128), 0, stream>>>(nfb, erec, offs,
                                                                 Wbg, bwt, be2, s_raw, denom, E);
  ctxgru_kernel<<<dim3(mb3), dim3(128), 0, stream>>>(s_raw, hvb, denom, Wet2, Wrz, Winn, Whn,
                                                     bet, b_ih, b_hh, out, N);
}

// Round 13
// 395.977 us; speedup vs baseline: 1.0421x; 1.0016x over previous
//
#include <hip/hip_runtime.h>
#include <hip/hip_bf16.h>

#define G 200
#define NDIM 32
#define EDIM 19
#define KIN 51  // NDIM + EDIM

typedef unsigned short u16;
typedef unsigned int u32;
typedef unsigned long long u64;

typedef __attribute__((ext_vector_type(8))) short bfrag;   // 8 bf16 (4 VGPRs)
typedef __attribute__((ext_vector_type(4))) float ffrag;   // 4 fp32 acc

__device__ __forceinline__ float lrelu(float x){ return x > 0.f ? x : 0.01f*x; }
__device__ __forceinline__ u16 f2b(float x){ u32 u = __float_as_uint(x); return (u16)((u + 0x7fffu + ((u >> 16) & 1u)) >> 16); }
__device__ __forceinline__ float b2f(u16 x){ return __uint_as_float(((u32)x) << 16); }
// HW packed f32->bf16 RNE pair -- used ONLY inside edge_csr's MFMA-interleaved staging
__device__ __forceinline__ u32 f2b2(float a, float b){
  u32 r;
  asm("v_cvt_pk_bf16_f32 %0, %1, %2" : "=v"(r) : "v"(a), "v"(b));
  return r;
}

#define MFMA16(a, b, c) __builtin_amdgcn_mfma_f32_16x16x32_bf16(a, b, c, 0, 0, 0)

// ---------------- init v2: nf->bf16 + degree hist + weight prep + bwt (zeroing via hipMemsetAsync) ----------------
__global__ void init_kernel(const int* __restrict__ dst, int* __restrict__ deg,
                            const float* __restrict__ nf, u16* __restrict__ nfb,
                            const float* __restrict__ We1, const float* __restrict__ Wn,
                            const float* __restrict__ Wet, const float* __restrict__ Wih,
                            const float* __restrict__ Whh,
                            const float* __restrict__ be1, const float* __restrict__ We2,
                            u16* __restrict__ Wbg, u16* __restrict__ Wnb, u16* __restrict__ Wet2,
                            u16* __restrict__ Wrz, u16* __restrict__ Winn, u16* __restrict__ Whn,
                            u32* __restrict__ bwt, int N, int E){
  int i = blockIdx.x * 256 + threadIdx.x;
  if (i < N * NDIM) nfb[i] = f2b(nf[i]);
  if (i < E) atomicAdd(&deg[dst[i]], 1);
  if (i < 208){
    float bv = (i < G) ? be1[i] : 0.f;
    float wv = (i < G) ? We2[G + i] : 0.f;
    bwt[i] = (u32)f2b(bv) | ((u32)f2b(wv) << 16);
  }

  int idx = i;
  const int s0 = 208 * 64, s1 = 256 * 64, s2 = 208 * 224, s3 = 2 * 208 * 416, s4 = 208 * 224, s5 = 208 * 224;
  if (idx < s0){
    int r = idx >> 6, k = idx & 63;
    Wbg[idx] = f2b((r < G && k < KIN) ? We1[r * KIN + k] : 0.f);
    return;
  }
  idx -= s0;
  if (idx < s1){
    int r = idx >> 6, k = idx & 63;
    Wnb[idx] = f2b((r < G && k < NDIM) ? Wn[r * NDIM + k] : 0.f);
    return;
  }
  idx -= s1;
  if (idx < s2){
    int r = idx / 224, k = idx % 224;
    Wet2[idx] = f2b((r < G && k < G) ? Wet[r * G + k] : 0.f);
    return;
  }
  idx -= s2;
  if (idx < s3){
    int g = idx / (208 * 416), rem = idx % (208 * 416);
    int r = rem / 416, k = rem % 416;
    float v = 0.f;
    if (r < G){
      int row = g * G + r;
      if (k < G) v = Wih[row * G + k];
      else if (k >= 208 && k < 408) v = Whh[row * G + (k - 208)];
    }
    Wrz[idx] = f2b(v);
    return;
  }
  idx -= s3;
  if (idx < s4){
    int r = idx / 224, k = idx % 224;
    Winn[idx] = f2b((r < G && k < G) ? Wih[(2 * G + r) * G + k] : 0.f);
    return;
  }
  idx -= s4;
  if (idx < s5){
    int r = idx / 224, kk = idx % 224;
    Whn[idx] = f2b((r < G && kk >= 16 && kk < 216) ? Whh[(2 * G + r) * G + (kk - 16)] : 0.f);
  }
}

// ---------------- single-pass block scan, LDS-staged coalesced loads ----------------
__global__ __launch_bounds__(1024) void scan_kernel(const int* __restrict__ deg, int* __restrict__ offs,
                                                    int* __restrict__ cur, int N){
  __shared__ int sd[12800];
  __shared__ int wsums[16];
  const int C = 25;  // 1024*25 = 25600 >= N
  int tid = threadIdx.x;
  int lane = tid & 63, wid = tid >> 6;
  int val[C];
  for (int h = 0; h < 2; ++h){
    int base_h = h * 12800;
    for (int k = tid; k < 12800; k += 1024){
      int gi = base_h + k;
      sd[k] = (gi < N) ? deg[gi] : 0;
    }
    __syncthreads();
    if ((tid >> 9) == h){
      int t0 = (tid - h * 512) * C;
      #pragma unroll
      for (int i = 0; i < C; ++i) val[i] = sd[t0 + i];
    }
    __syncthreads();
  }
  int s = 0;
  #pragma unroll
  for (int i = 0; i < C; ++i){ int v = val[i]; val[i] = s; s += v; }
  int x = s;
  #pragma unroll
  for (int off = 1; off < 64; off <<= 1){
    int y = __shfl_up(x, off, 64);
    if (lane >= off) x += y;
  }
  if (lane == 63) wsums[wid] = x;
  __syncthreads();
  if (wid == 0){
    int w = (lane < 16) ? wsums[lane] : 0;
    #pragma unroll
    for (int off = 1; off < 16; off <<= 1){
      int y = __shfl_up(w, off, 64);
      if (lane >= off) w += y;
    }
    if (lane < 16) wsums[lane] = w;
  }
  __syncthreads();
  int excl = ((wid ? wsums[wid - 1] : 0) + x) - s;
  int base = tid * C;
  #pragma unroll
  for (int i = 0; i < C; ++i){
    int o = excl + val[i];
    if (base + i < N){ offs[base + i] = o; cur[base + i] = o; }
  }
  if (tid == 1023) offs[N] = excl + s;
}

// ---------------- scatter + pack: ONE aligned 64B record per edge ----------------
// record (u32[16]): [0]=dst [1]=src [2]=l1[dst] bits [3]=0 [4..15]=24 bf16 edge feats
__global__ void scatter_pack_kernel(const int* __restrict__ dst, const int* __restrict__ src,
                                    const float* __restrict__ ef, const float* __restrict__ l1,
                                    int* __restrict__ cur, u32* __restrict__ erec, int E){
  int e = blockIdx.x * 256 + threadIdx.x;
  if (e >= E) return;
  int d = dst[e];
  int pos = atomicAdd(&cur[d], 1);
  u32 w[16];
  w[0] = (u32)d; w[1] = (u32)src[e]; w[2] = __float_as_uint(l1[d]); w[3] = 0u;
  const float* ep = ef + (long)e * EDIM;
  #pragma unroll
  for (int j = 0; j < 9; ++j) w[4 + j] = (u32)f2b(ep[2 * j]) | ((u32)f2b(ep[2 * j + 1]) << 16);
  w[13] = (u32)f2b(ep[18]);
  w[14] = 0u; w[15] = 0u;
  uint4* dp = (uint4*)(erec + (size_t)pos * 16);
  dp[0] = make_uint4(w[0], w[1], w[2], w[3]);
  dp[1] = make_uint4(w[4], w[5], w[6], w[7]);
  dp[2] = make_uint4(w[8], w[9], w[10], w[11]);
  dp[3] = make_uint4(w[12], w[13], w[14], w[15]);
}

// ---------------- hv GEMM v2: A-tile loaded directly from nfb (bf16, L2-hot) -- no f2b staging ----------------
__global__ __launch_bounds__(256) void hvgemm_kernel(
    const u16* __restrict__ nfb, const u16* __restrict__ Wnb, const float* __restrict__ bn,
    const float* __restrict__ We2, u16* __restrict__ hvb, float* __restrict__ l1, int M)
{
  __shared__ __align__(16) u16 As[64][72];
  __shared__ __align__(16) u16 Ws[64][72];
  int tid = threadIdx.x;
  int m0 = blockIdx.y * 64, n0 = blockIdx.x * 64;
  int l = tid & 63, w = tid >> 6, quad = l >> 4, col = l & 15;

  // A: 64 rows x 64 cols bf16 (cols 32..63 zero); 16B chunks, pure copies from nfb
  for (int idx = tid; idx < 64 * 8; idx += 256){
    int r = idx >> 3, c = idx & 7;
    int row = m0 + r;
    ulonglong2 v; v.x = 0; v.y = 0;
    if (row < M && c < 4) v = *(const ulonglong2*)(nfb + (long)row * NDIM + c * 8);
    *(ulonglong2*)&As[r][c * 8] = v;
  }
  for (int idx = tid; idx < 64 * 8; idx += 256){
    int r = idx >> 3, c = idx & 7;
    *(ulonglong2*)&Ws[r][c * 8] = *(const ulonglong2*)(Wnb + (long)(n0 + r) * 64 + c * 8);
  }
  __syncthreads();
  bfrag a0 = *(const bfrag*)&As[w * 16 + col][quad * 8];
  bfrag a1 = *(const bfrag*)&As[w * 16 + col][32 + quad * 8];
  ffrag acc[4];
  #pragma unroll
  for (int t = 0; t < 4; ++t){ acc[t].x = 0.f; acc[t].y = 0.f; acc[t].z = 0.f; acc[t].w = 0.f; }
  #pragma unroll
  for (int t = 0; t < 4; ++t){
    bfrag b0 = *(const bfrag*)&Ws[t * 16 + col][quad * 8];
    bfrag b1 = *(const bfrag*)&Ws[t * 16 + col][32 + quad * 8];
    acc[t] = MFMA16(a0, b0, acc[t]);
    acc[t] = MFMA16(a1, b1, acc[t]);
  }
  float lp[4] = {0.f, 0.f, 0.f, 0.f};
  #pragma unroll
  for (int t = 0; t < 4; ++t){
    int n = n0 + t * 16 + col;
    float bv = (n < G) ? bn[n] : 0.f;
    float wv = (n < G) ? We2[n] : 0.f;
    #pragma unroll
    for (int r = 0; r < 4; ++r){
      int row = m0 + w * 16 + quad * 4 + r;
      float v = lrelu(acc[t][r] + bv);
      lp[r] += wv * v;
      if (n < G && row < M) hvb[(long)row * G + n] = f2b(v);
    }
  }
  #pragma unroll
  for (int r = 0; r < 4; ++r){
    lp[r] += __shfl_xor(lp[r], 1, 16);
    lp[r] += __shfl_xor(lp[r], 2, 16);
    lp[r] += __shfl_xor(lp[r], 4, 16);
    lp[r] += __shfl_xor(lp[r], 8, 16);
  }
  if (col == 0){
    #pragma unroll
    for (int r = 0; r < 4; ++r){
      int row = m0 + w * 16 + quad * 4 + r;
      if (row < M) atomicAdd(&l1[row], lp[r]);
    }
  }
}

// ---------------- CSR edge kernel v10 (FROZEN): best-measured state ----------------
#define SST 72
__global__ __launch_bounds__(128, 2) void edge_csr_kernel(
    const u16* __restrict__ nfb, const u32* __restrict__ erec, const int* __restrict__ offs,
    const u16* __restrict__ Wbg, const u32* __restrict__ bwt, const float* __restrict__ be2,
    float* __restrict__ s_raw, float* __restrict__ denom, int E)
{
  __shared__ __align__(16) u16 shm[208 * SST];  // stageT [208][72]
  __shared__ int segnode[64];
  __shared__ __align__(16) u16 exb[64];
  __shared__ __align__(8) unsigned char segb[64];
  __shared__ int Svar;

  int tid = threadIdx.x;
  int j0 = blockIdx.x * 64;
  int l = tid & 63, w = tid >> 6;        // w in {0,1}
  int quad = l >> 4, col = l & 15;
  int m0a = w * 32, m0b = w * 32 + 16;

  // ---- issue longest-latency chains first: src index -> nfb gather (HBM-random) ----
  int ja = j0 + m0a + col;
  int jb = j0 + m0b + col;
  bool va = ja < E, vb = jb < E;
  int sa = va ? (int)erec[(size_t)ja * 16 + 1] : 0;
  int sb = vb ? (int)erec[(size_t)jb * 16 + 1] : 0;
  bfrag a0a = {0,0,0,0,0,0,0,0}, a1a = {0,0,0,0,0,0,0,0};
  bfrag a0b = {0,0,0,0,0,0,0,0}, a1b = {0,0,0,0,0,0,0,0};
  if (va){
    a0a = *(const bfrag*)(nfb + (long)sa * NDIM + quad * 8);
    if (quad < 3) a1a = *(const bfrag*)((const u16*)erec + (size_t)ja * 32 + 8 + quad * 8);
  }
  if (vb){
    a0b = *(const bfrag*)(nfb + (long)sb * NDIM + quad * 8);
    if (quad < 3) a1b = *(const bfrag*)((const u16*)erec + (size_t)jb * 32 + 8 + quad * 8);
  }

  // ---- prefetch ALL B fragments + bias/weight words into registers (L2-hot burst) ----
  bfrag B0[13], B1[13];
  u32 bwp[13];
  #pragma unroll
  for (int t = 0; t < 13; ++t){
    B0[t] = *(const bfrag*)(Wbg + (t * 16 + col) * 64 + quad * 8);
    B1[t] = *(const bfrag*)(Wbg + (t * 16 + col) * 64 + 32 + quad * 8);
    bwp[t] = bwt[t * 16 + col];
  }

  // ---- meta: wave 0 only (overlaps the loads above) ----
  if (tid < 64){
    int j = j0 + tid;
    int valid = j < E;
    int n = valid ? (int)erec[(size_t)j * 16] : -1;
    int nn = (tid == 63 || j + 1 >= E) ? -2 : (int)erec[(size_t)(j + 1) * 16];
    int f1 = (valid && n != nn) ? 1 : 0;
    int f2 = 0;
    if (f1 && offs[n] >= j0 && offs[n + 1] <= j0 + 64) f2 = 1;
    u64 em = __ballot(f1 != 0);
    int seg = (int)__popcll(em & ((1ull << tid) - 1ull));
    segb[tid] = (unsigned char)seg;
    if (f1) segnode[seg] = (n << 1) | f2;
    if (tid == 0) Svar = (int)__popcll(em);
    shm[200 * SST + tid] = 0x3F80;  // ones row (for denom)
  }

  // ---- phase 1: 13 he1 tiles x 2 strips, pure-register operands ----
  float pla[4] = {0.f, 0.f, 0.f, 0.f};
  float plb[4] = {0.f, 0.f, 0.f, 0.f};
  #pragma unroll
  for (int t = 0; t < 13; ++t){
    ffrag acca; acca.x = 0.f; acca.y = 0.f; acca.z = 0.f; acca.w = 0.f;
    ffrag accb; accb.x = 0.f; accb.y = 0.f; accb.z = 0.f; accb.w = 0.f;
    acca = MFMA16(a0a, B0[t], acca);
    acca = MFMA16(a1a, B1[t], acca);
    accb = MFMA16(a0b, B0[t], accb);
    accb = MFMA16(a1b, B1[t], accb);
    int g = t * 16 + col;
    u32 bw = bwp[t];
    float bv = b2f((u16)(bw & 0xFFFF)), wv = b2f((u16)(bw >> 16));
    float u0 = lrelu(acca.x + bv), u1 = lrelu(acca.y + bv);
    float u2 = lrelu(acca.z + bv), u3 = lrelu(acca.w + bv);
    pla[0] += wv * u0; pla[1] += wv * u1; pla[2] += wv * u2; pla[3] += wv * u3;
    float v0 = lrelu(accb.x + bv), v1 = lrelu(accb.y + bv);
    float v2 = lrelu(accb.z + bv), v3 = lrelu(accb.w + bv);
    plb[0] += wv * v0; plb[1] += wv * v1; plb[2] += wv * v2; plb[3] += wv * v3;
    if (g < G){
      *(uint2*)&shm[g * SST + m0a + quad * 4] = make_uint2(f2b2(u0, u1), f2b2(u2, u3));
      *(uint2*)&shm[g * SST + m0b + quad * 4] = make_uint2(f2b2(v0, v1), f2b2(v2, v3));
    }
  }
  #pragma unroll
  for (int r = 0; r < 4; ++r){
    pla[r] += __shfl_xor(pla[r], 1, 16);
    pla[r] += __shfl_xor(pla[r], 2, 16);
    pla[r] += __shfl_xor(pla[r], 4, 16);
    pla[r] += __shfl_xor(pla[r], 8, 16);
    plb[r] += __shfl_xor(plb[r], 1, 16);
    plb[r] += __shfl_xor(plb[r], 2, 16);
    plb[r] += __shfl_xor(plb[r], 4, 16);
    plb[r] += __shfl_xor(plb[r], 8, 16);
  }
  if (col == 0){
    #pragma unroll
    for (int r = 0; r < 4; ++r){
      int ea = m0a + quad * 4 + r;
      float exa = 0.f;
      if (j0 + ea < E){
        float l1v = __uint_as_float(erec[(size_t)(j0 + ea) * 16 + 2]);
        exa = __expf(lrelu(pla[r] + l1v + be2[0]));
      }
      exb[ea] = f2b(exa);
      int eb = m0b + quad * 4 + r;
      float exv = 0.f;
      if (j0 + eb < E){
        float l1v = __uint_as_float(erec[(size_t)(j0 + eb) * 16 + 2]);
        exv = __expf(lrelu(plb[r] + l1v + be2[0]));
      }
      exb[eb] = f2b(exv);
    }
  }
  __syncthreads();  // the ONLY barrier

  // ---- phase 2: MFMA segment reduction (tiles 0..6 -> wave 0, 7..12 -> wave 1) ----
  int S = Svar;
  for (int mt = 0; mt * 16 < S; ++mt){
    int m = mt * 16 + col;
    u64 sb0 = *(const u64*)&segb[quad * 8];
    u64 sb1 = *(const u64*)&segb[32 + quad * 8];
    ulonglong2 ew0 = *(const ulonglong2*)&exb[quad * 8];
    ulonglong2 ew1 = *(const ulonglong2*)&exb[32 + quad * 8];
    bfrag A0, A1;
    #pragma unroll
    for (int jj = 0; jj < 8; ++jj){
      int s0i = (int)((sb0 >> (8 * jj)) & 0xFF);
      int s1i = (int)((sb1 >> (8 * jj)) & 0xFF);
      u64 w0 = (jj < 4) ? ew0.x : ew0.y;
      u64 w1 = (jj < 4) ? ew1.x : ew1.y;
      u16 e0 = (u16)(w0 >> (16 * (jj & 3)));
      u16 e1 = (u16)(w1 >> (16 * (jj & 3)));
      A0[jj] = (s0i == m) ? (short)e0 : (short)0;
      A1[jj] = (s1i == m) ? (short)e1 : (short)0;
    }
    int t0 = (w == 0) ? 0 : 7;
    int cnt = (w == 0) ? 7 : 6;
    for (int i = 0; i < cnt; ++i){
      int t = t0 + i;
      bfrag b0 = *(const bfrag*)&shm[(t * 16 + col) * SST + quad * 8];
      bfrag b1 = *(const bfrag*)&shm[(t * 16 + col) * SST + 32 + quad * 8];
      ffrag acc; acc.x = 0.f; acc.y = 0.f; acc.z = 0.f; acc.w = 0.f;
      acc = MFMA16(A0, b0, acc);
      acc = MFMA16(A1, b1, acc);
      int g = t * 16 + col;
      #pragma unroll
      for (int r = 0; r < 4; ++r){
        int seg = mt * 16 + quad * 4 + r;
        if (seg < S && g <= 200){
          int enc = segnode[seg];
          int nd = enc >> 1;
          float v = acc[r];
          float* pd = (g < G) ? (s_raw + (long)nd * G + g) : (denom + nd);
          if (enc & 1) *pd = v; else atomicAdd(pd, v);
        }
      }
    }
  }
}

// ---------------- fused ctx + GRU kernel v4 (KEPT): 16 rows/block, 2 waves splitting column tiles ----------------
#define XST 420
__global__ __launch_bounds__(128, 2) void ctxgru_kernel(
    const float* __restrict__ s_raw, const u16* __restrict__ hvb, const float* __restrict__ denom,
    const u16* __restrict__ Wet2, const u16* __restrict__ Wrz,
    const u16* __restrict__ Winn, const u16* __restrict__ Whn,
    const float* __restrict__ bet, const float* __restrict__ b_ih, const float* __restrict__ b_hh,
    float* __restrict__ out, int M)
{
  __shared__ __align__(16) u16 X[16 * XST];
  __shared__ float invds[16];
  int tid = threadIdx.x;
  int m0 = blockIdx.x * 16;

  if (tid < 16){
    float dn = (m0 + tid < M) ? denom[m0 + tid] : 0.f;
    invds[tid] = dn > 0.f ? 1.f / dn : 0.f;
  }
  __syncthreads();

  for (int idx = tid; idx < 16 * 50; idx += 128){
    int r = idx / 50, c = idx % 50;
    int row = m0 + r;
    float4 v = make_float4(0.f,0.f,0.f,0.f);
    ushort4 h = make_ushort4(0,0,0,0);
    if (row < M){
      v = *(const float4*)(s_raw + (long)row * G + c * 4);
      h = *(const ushort4*)(hvb + (long)row * G + c * 4);
    }
    float iv = invds[r];
    *(ushort4*)&X[r * XST + c * 4] = make_ushort4(f2b(v.x*iv), f2b(v.y*iv), f2b(v.z*iv), f2b(v.w*iv));
    *(ushort4*)&X[r * XST + 208 + c * 4] = h;
  }
  for (int idx = tid; idx < 16 * 4; idx += 128){
    int r = idx / 4, q = idx % 4;
    int base = (q < 2) ? (200 + q * 4) : (408 + (q - 2) * 4);
    *(ushort4*)&X[r * XST + base] = make_ushort4(0,0,0,0);
  }
  __syncthreads();

  int l = tid & 63, w = tid >> 6, quad = l >> 4, col = l & 15;
  int st0 = (w == 0) ? 0 : 7;
  int stn = (w == 0) ? 7 : 6;

  // ---- phase 1: ctx (wave w computes its 7/6 column tiles for all 16 rows) ----
  bfrag a1[7];
  #pragma unroll
  for (int j = 0; j < 7; ++j) a1[j] = *(const bfrag*)&X[col * XST + j * 32 + quad * 8];

  for (int ii = 0; ii < stn; ++ii){
    int st = st0 + ii;
    int n = st * 16 + col;
    ffrag acc; acc.x = 0.f; acc.y = 0.f; acc.z = 0.f; acc.w = 0.f;
    #pragma unroll
    for (int j = 0; j < 7; ++j){
      bfrag b = *(const bfrag*)(Wet2 + (long)n * 224 + j * 32 + quad * 8);
      acc = MFMA16(a1[j], b, acc);
    }
    if (n < G){
      float bv = bet[n];
      #pragma unroll
      for (int r = 0; r < 4; ++r){
        int lr = quad * 4 + r;
        float gate = invds[lr] > 0.f ? 1.f : 0.f;
        float v = acc[r] + gate * bv;
        v = (v > 0.f) ? v : (__expf(v) - 1.f);
        X[lr * XST + n] = f2b(v);
      }
    }
  }
  __syncthreads();

  // ---- phase 2: gates + GRU (same 7/6 split) ----
  bfrag a2[13];
  #pragma unroll
  for (int j = 0; j < 13; ++j) a2[j] = *(const bfrag*)&X[col * XST + j * 32 + quad * 8];

  for (int ii = 0; ii < stn; ++ii){
    int st = st0 + ii;
    int n = st * 16 + col;
    ffrag ar, az, ai, ah;
    ar.x=ar.y=ar.z=ar.w=0.f; az.x=az.y=az.z=az.w=0.f;
    ai.x=ai.y=ai.z=ai.w=0.f; ah.x=ah.y=ah.z=ah.w=0.f;
    #pragma unroll
    for (int j = 0; j < 13; ++j){
      bfrag br_ = *(const bfrag*)(Wrz + (long)n * 416 + j * 32 + quad * 8);
      ar = MFMA16(a2[j], br_, ar);
      bfrag bz_ = *(const bfrag*)(Wrz + (long)(208 + n) * 416 + j * 32 + quad * 8);
      az = MFMA16(a2[j], bz_, az);
    }
    #pragma unroll
    for (int j = 0; j < 7; ++j){
      bfrag bi_ = *(const bfrag*)(Winn + (long)n * 224 + j * 32 + quad * 8);
      ai = MFMA16(a2[j], bi_, ai);
      bfrag bh_ = *(const bfrag*)(Whn + (long)n * 224 + j * 32 + quad * 8);
      ah = MFMA16(a2[j + 6], bh_, ah);
    }
    if (n < G){
      float br = b_ih[n] + b_hh[n];
      float bz = b_ih[G + n] + b_hh[G + n];
      float bi = b_ih[2 * G + n];
      float bh = b_hh[2 * G + n];
      #pragma unroll
      for (int r = 0; r < 4; ++r){
        int lr = quad * 4 + r;
        int row = m0 + lr;
        if (row < M){
          float rg = 1.f / (1.f + __expf(-(ar[r] + br)));
          float zg = 1.f / (1.f + __expf(-(az[r] + bz)));
          float ng = tanhf(ai[r] + bi + rg * (ah[r] + bh));
          float hvv = b2f(X[lr * XST + 208 + n]);
          float h = (1.f - zg) * ng + zg * hvv;
          out[(long)row * G + n] = h > 0.f ? h : 0.f;
        }
      }
    }
  }
}

extern "C" void kernel_launch(void* const* d_in, const int* in_sizes, int n_in,
                              void* d_out, int out_size, void* d_ws, size_t ws_size,
                              hipStream_t stream)
{
  const float* nf   = (const float*)d_in[0];
  const float* ef   = (const float*)d_in[1];
  const int*   src  = (const int*)d_in[2];
  const int*   dst  = (const int*)d_in[3];
  const float* Wn   = (const float*)d_in[4];
  const float* bn   = (const float*)d_in[5];
  const float* We1  = (const float*)d_in[6];
  const float* be1  = (const float*)d_in[7];
  const float* We2  = (const float*)d_in[8];
  const float* be2  = (const float*)d_in[9];
  const float* Wet  = (const float*)d_in[10];
  const float* bet  = (const float*)d_in[11];
  const float* W_ih = (const float*)d_in[12];
  const float* b_ih = (const float*)d_in[13];
  const float* W_hh = (const float*)d_in[14];
  const float* b_hh = (const float*)d_in[15];
  int N = in_sizes[0] / NDIM;   // 25000
  int E = in_sizes[2];          // 500000
  float* out = (float*)d_out;

  char* p = (char*)d_ws;
  auto alloc = [&](size_t b){ char* r = p; p += (b + 255) & ~(size_t)255; return r; };
  u16*   hvb   = (u16*)  alloc((size_t)N * G * 2);
  float* s_raw = (float*)alloc((size_t)N * G * 4);
  int*   zb    = (int*)  alloc((size_t)3 * N * 4);   // [denom | deg | l1] contiguous, one memset
  float* denom = (float*)zb;
  int*   deg   = zb + N;
  float* l1    = (float*)(zb + 2 * N);
  int*   offs  = (int*)  alloc((size_t)(N + 1) * 4);
  int*   cur   = (int*)  alloc((size_t)N * 4);
  u32*   erec  = (u32*)  alloc((size_t)E * 64);
  u16*   nfb   = (u16*)  alloc((size_t)N * NDIM * 2);
  u16*   Wbg   = (u16*)  alloc((size_t)208 * 64 * 2);
  u16*   Wnb   = (u16*)  alloc((size_t)256 * 64 * 2);
  u16*   Wet2  = (u16*)  alloc((size_t)208 * 224 * 2);
  u16*   Wrz   = (u16*)  alloc((size_t)2 * 208 * 416 * 2);
  u16*   Winn  = (u16*)  alloc((size_t)208 * 224 * 2);
  u16*   Whn   = (u16*)  alloc((size_t)208 * 224 * 2);
  u32*   bwt   = (u32*)  alloc((size_t)208 * 4);

  int eb = (E + 255) / 256;
  int mb = (N + 63) / 64;
  int mb3 = (N + 15) / 16;
  int ib = (N * NDIM + 255) / 256;   // 3125 blocks: covers N*NDIM=800K > E=500K > prep_total=342K

  hipMemsetAsync(s_raw, 0, (size_t)N * G * 4, stream);
  hipMemsetAsync(zb, 0, (size_t)3 * N * 4, stream);
  init_kernel<<<dim3(ib), dim3(256), 0, stream>>>(
      dst, deg, nf, nfb, We1, Wn, Wet, W_ih, W_hh, be1, We2,
      Wbg, Wnb, Wet2, Wrz, Winn, Whn, bwt, N, E);
  scan_kernel<<<dim3(1), dim3(1024), 0, stream>>>(deg, offs, cur, N);
  hvgemm_kernel<<<dim3(4, mb), dim3(256), 0, stream>>>(nfb, Wnb, bn, We2, hvb, l1, N);
  scatter_pack_kernel<<<dim3(eb), dim3(256), 0, stream>>>(dst, src, ef, l1, cur, erec, E);
  edge_csr_kernel<<<dim3((E + 63) / 64), dim3(128), 0, stream>>>(nfb, erec, offs,
                                                                 Wbg, bwt, be2, s_raw, denom, E);
  ctxgru_kernel<<<dim3(mb3), dim3(128), 0, stream>>>(s_raw, hvb, denom, Wet2, Wrz, Winn, Whn,
                                                     bet, b_ih, b_hh, out, N);
}